// Round 7
// baseline (6997.514 us; speedup 1.0000x reference)
//
#include <hip/hip_runtime.h>
#include <math.h>

#define B_   4096
#define S_   64
#define H_   128
#define N_   (B_*S_)

// ---- workspace float offsets ----
#define WS_WC    0        // [384][16]  combined obs->gi weights (padded f=16)
#define WS_BC    6144     // [384]      combined gi bias
#define WS_WAP   6528     // [128][16]  padded enc_air_w
#define WS_WQP   8576     // [128][128] wq * qln_w (folded)
#define WS_SQ    24960    // [128] row sums of wqp
#define WS_EQ    25088    // [128] wq@qln_b + bq
#define WS_KC    25216    // [128][4]  (wk*klnw)@enc_m_w
#define WS_EK1   25728    // [128] (wk*klnw)@enc_m_b
#define WS_SK    25856    // [128] rowsum(wk*klnw)
#define WS_EK2   25984    // [128] wk@kln_b + bk
#define WS_VC    26112    // [128][4]  wv@enc_m_w
#define WS_VB    26624    // [128] wv@enc_m_b + bv
#define WS_MV    26752    // [4] mean weights for keys_raw mean
#define WS_QQ    26756    // [16] 4x4 quadratic form for E[y^2]
#define WS_QLIN  26772    // [4]
#define WS_MBC   26776
#define WS_C0    26777
#define WS_AIR   27392    // [N_][128] air_feat buffer

#define AP 172     // attn row pitch
#define GP_ROW 148 // gru h row pitch (4 chunks * 36 + 4)
#define GP_CH  36  // gru chunk pitch: words 0..31 = h, 32..35 = obs slack

__device__ __forceinline__ float dot4(float4 a, float4 b){
    return fmaf(a.x,b.x, fmaf(a.y,b.y, fmaf(a.z,b.z, a.w*b.w)));
}
__device__ __forceinline__ void acc4(float& acc, float4 a, float4 b){
    acc = fmaf(a.x,b.x,acc); acc = fmaf(a.y,b.y,acc);
    acc = fmaf(a.z,b.z,acc); acc = fmaf(a.w,b.w,acc);
}
__device__ __forceinline__ float sel4(const float v[4], int kc){
    float a = (kc&1) ? v[1] : v[0];
    float b = (kc&1) ? v[3] : v[2];
    return (kc&2) ? b : a;
}
__device__ __forceinline__ int caddr(int r, int c){       // attn chunked layout
    return r*AP + (c>>5)*40 + (c&31);
}

// ---------------- precompute folded weights ----------------
__global__ void precompute_kernel(
    const float* __restrict__ enc_air_w, const float* __restrict__ enc_air_b,
    const float* __restrict__ enc_m_w,  const float* __restrict__ enc_m_b,
    const float* __restrict__ gru_wih,  const float* __restrict__ gru_bih,
    const float* __restrict__ qln_w, const float* __restrict__ qln_b,
    const float* __restrict__ kln_w, const float* __restrict__ kln_b,
    const float* __restrict__ attn_in_w, const float* __restrict__ attn_in_b,
    float* __restrict__ ws)
{
    int i = blockIdx.x*blockDim.x + threadIdx.x;
    if (i < 6144) {                       // Wc[o][f] = sum_k wih[o][k]*Wa[k][f]
        int o = i>>4, f = i&15; float a = 0.f;
        if (f < 15) for (int k=0;k<128;k++) a = fmaf(gru_wih[o*128+k], enc_air_w[k*15+f], a);
        ws[WS_WC+i] = a;
    } else if (i < 6528) {                // bc
        int o = i-6144; float a = gru_bih[o];
        for (int k=0;k<128;k++) a = fmaf(gru_wih[o*128+k], enc_air_b[k], a);
        ws[WS_BC+o] = a;
    } else if (i < 8576) {                // Wap padded
        int idx = i-6528; int j = idx>>4, f = idx&15;
        ws[WS_WAP+idx] = (f<15) ? enc_air_w[j*15+f] : 0.f;
    } else if (i < 24960) {               // wqp
        int idx = i-8576; int o = idx>>7, j = idx&127;
        ws[WS_WQP+idx] = attn_in_w[o*128+j]*qln_w[j];
    } else if (i < 25088) {               // sq
        int o = i-24960; float a=0.f;
        for (int j=0;j<128;j++) a = fmaf(attn_in_w[o*128+j], qln_w[j], a);
        ws[WS_SQ+o]=a;
    } else if (i < 25216) {               // eq
        int o = i-25088; float a = attn_in_b[o];
        for (int j=0;j<128;j++) a = fmaf(attn_in_w[o*128+j], qln_b[j], a);
        ws[WS_EQ+o]=a;
    } else if (i < 25728) {               // Kc
        int idx = i-25216; int o = idx>>2, f = idx&3; float a=0.f;
        for (int j=0;j<128;j++) a = fmaf(attn_in_w[(128+o)*128+j]*kln_w[j], enc_m_w[j*4+f], a);
        ws[WS_KC+idx]=a;
    } else if (i < 25856) {               // ek1
        int o = i-25728; float a=0.f;
        for (int j=0;j<128;j++) a = fmaf(attn_in_w[(128+o)*128+j]*kln_w[j], enc_m_b[j], a);
        ws[WS_EK1+o]=a;
    } else if (i < 25984) {               // sk
        int o = i-25856; float a=0.f;
        for (int j=0;j<128;j++) a = fmaf(attn_in_w[(128+o)*128+j], kln_w[j], a);
        ws[WS_SK+o]=a;
    } else if (i < 26112) {               // ek2
        int o = i-25984; float a = attn_in_b[128+o];
        for (int j=0;j<128;j++) a = fmaf(attn_in_w[(128+o)*128+j], kln_b[j], a);
        ws[WS_EK2+o]=a;
    } else if (i < 26624) {               // Vc
        int idx = i-26112; int o = idx>>2, f = idx&3; float a=0.f;
        for (int j=0;j<128;j++) a = fmaf(attn_in_w[(256+o)*128+j], enc_m_w[j*4+f], a);
        ws[WS_VC+idx]=a;
    } else if (i < 26752) {               // vb
        int o = i-26624; float a = attn_in_b[256+o];
        for (int j=0;j<128;j++) a = fmaf(attn_in_w[(256+o)*128+j], enc_m_b[j], a);
        ws[WS_VB+o]=a;
    } else if (i < 26756) {               // Mv
        int f = i-26752; float a=0.f;
        for (int j=0;j<128;j++) a += enc_m_w[j*4+f];
        ws[WS_MV+f]=a*(1.f/128.f);
    } else if (i < 26772) {               // QQ
        int idx = i-26756; int a4 = idx>>2, b4 = idx&3; float a=0.f;
        for (int j=0;j<128;j++) a = fmaf(enc_m_w[j*4+a4], enc_m_w[j*4+b4], a);
        ws[WS_QQ+idx]=a*(1.f/128.f);
    } else if (i < 26776) {               // qlin
        int f = i-26772; float a=0.f;
        for (int j=0;j<128;j++) a = fmaf(enc_m_b[j], enc_m_w[j*4+f], a);
        ws[WS_QLIN+f]=a*(2.f/128.f);
    } else if (i == 26776) {
        float a=0.f; for (int j=0;j<128;j++) a += enc_m_b[j];
        ws[WS_MBC]=a*(1.f/128.f);
    } else if (i == 26777) {
        float a=0.f; for (int j=0;j<128;j++) a = fmaf(enc_m_b[j], enc_m_b[j], a);
        ws[WS_C0]=a*(1.f/128.f);
    }
}

// ---------------- Kernel A: GRU, 512 threads ----------------
// 256 blocks x 16 rows. Thread (j=t>>2, kc=t&3) owns whh[gate][j][32kc..32kc+32)
// = 24 float4 persistent + obs-fold float4 x2. Wc_n/Wap rows in LDS; obs staged
// in the h-chunk slack words. 4-row groups, quartet shfl reduce, immediate
// finalize. waves_per_eu(2,2): max=2 forbids the allocator's high-occupancy
// choice -> register budget ~256, no spill (R6 evidence: min-only forms fail).
__global__ __launch_bounds__(512) __attribute__((amdgpu_waves_per_eu(2, 2)))
void gru_kernel(
    const float* __restrict__ obs, const float* __restrict__ h0,
    const float* __restrict__ whh, const float* __restrict__ bhh,
    const float* __restrict__ ba,  const float* __restrict__ ws,
    float* __restrict__ air, float* __restrict__ out)
{
    __shared__ float h_s[2][16*GP_ROW];
    __shared__ float air_s[16*132];
    __shared__ float wn_s[128*20];     // Wc_n rows, pitch 20
    __shared__ float wap_s[128*20];    // Wap rows, pitch 20

    const int t  = threadIdx.x;
    const int j  = t>>2;        // 0..127 output column
    const int kc = t&3;         // 0..3 k-chunk (32 floats)
    const int row0 = blockIdx.x*16;

    // --- persistent weights: 96 + 8 floats ---
    const float4* whh4 = (const float4*)whh;
    const float4* ws4  = (const float4*)ws;
    float4 whr[8], whz[8], whn[8];
    #pragma unroll
    for (int i=0;i<8;i++){
        whr[i] = whh4[(      j)*32 + kc*8 + i];
        whz[i] = whh4[(128 + j)*32 + kc*8 + i];
        whn[i] = whh4[(256 + j)*32 + kc*8 + i];
    }
    const float4 wcr4 = ws4[(WS_WC>>2) + (      j)*4 + kc];   // obs cols 4kc..4kc+3
    const float4 wcz4 = ws4[(WS_WC>>2) + (128 + j)*4 + kc];
    const float bcrt = ws[WS_BC+j]     + bhh[j];
    const float bczt = ws[WS_BC+128+j] + bhh[128+j];
    const float bcn  = ws[WS_BC+256+j];
    const float bhn  = bhh[256+j];
    const float baj  = ba[j];
    const int hoff_j = (j>>5)*GP_CH + (j&31);

    // --- stage Wc_n / Wap into LDS (512 thr x 4 iters covers 128x16) ---
    {
        int f = t&15;
        #pragma unroll
        for (int it=0; it<4; it++){
            int jr = (t>>4) + 32*it;
            wn_s [jr*20+f] = ws[WS_WC + (256+jr)*16 + f];
            wap_s[jr*20+f] = ws[WS_WAP + jr*16 + f];
        }
    }
    // --- stage h0 + obs(0) into buf0 ---
    {
        int rr = t>>5, c0 = (t&31)*4;
        float4 hv = *(const float4*)&h0[(size_t)(row0+rr)*128 + c0];
        *(float4*)&h_s[0][rr*GP_ROW + (c0>>5)*GP_CH + (c0&31)] = hv;
    }
    if (t < 256){
        int rr = t>>4, c = t&15;
        h_s[0][rr*GP_ROW + (c>>2)*GP_CH + 32 + (c&3)] =
            (c<15) ? obs[((size_t)(row0+rr)*64 + 0)*15 + c] : 0.f;
    }
    __syncthreads();

    for (int s=0;s<64;s++){
        const float* hcur = h_s[s&1];
        float*       hnxt = h_s[(s+1)&1];

        // prefetch obs(s+1) into a register (overlaps the dot phase)
        float obs_pf = 0.f;
        if (t < 256){
            int rr = t>>4, c = t&15;
            int sn = (s<63) ? s+1 : s;
            obs_pf = (c<15) ? obs[((size_t)(row0+rr)*64 + sn)*15 + c] : 0.f;
        }

        #pragma unroll
        for (int g=0; g<4; g++){
            float pr[4],pz[4],pn[4];
            #pragma unroll
            for (int rq=0;rq<4;rq++){ pr[rq]=0.f; pz[rq]=0.f; pn[rq]=0.f; }
            #pragma unroll
            for (int rq=0;rq<4;rq++){
                const float* hb = &hcur[(g*4+rq)*GP_ROW + kc*GP_CH];
                #pragma unroll
                for (int i=0;i<8;i++){
                    float4 hv = *(const float4*)&hb[i*4];
                    acc4(pr[rq],hv,whr[i]); acc4(pz[rq],hv,whz[i]); acc4(pn[rq],hv,whn[i]);
                }
                float4 o4 = *(const float4*)&hb[32];   // obs slack for this chunk
                acc4(pr[rq], o4, wcr4);
                acc4(pz[rq], o4, wcz4);
            }
            // reduce over kc quartet (lanes differ in bits 0..1)
            #pragma unroll
            for (int rq=0;rq<4;rq++){
                pr[rq] += __shfl_xor(pr[rq],1); pr[rq] += __shfl_xor(pr[rq],2);
                pz[rq] += __shfl_xor(pz[rq],1); pz[rq] += __shfl_xor(pz[rq],2);
                pn[rq] += __shfl_xor(pn[rq],1); pn[rq] += __shfl_xor(pn[rq],2);
            }
            // lane kc finalizes row g*4+kc immediately (all lanes busy)
            const int r = g*4 + kc;
            float sr = sel4(pr,kc), sz = sel4(pz,kc), sn = sel4(pn,kc);
            const float* rb = &hcur[r*GP_ROW];
            float4 o0 = *(const float4*)&rb[32];
            float4 o1 = *(const float4*)&rb[GP_CH+32];
            float4 o2 = *(const float4*)&rb[2*GP_CH+32];
            float4 o3 = *(const float4*)&rb[3*GP_CH+32];
            float gin = bcn;
            acc4(gin,o0,*(const float4*)&wn_s[j*20+ 0]);
            acc4(gin,o1,*(const float4*)&wn_s[j*20+ 4]);
            acc4(gin,o2,*(const float4*)&wn_s[j*20+ 8]);
            acc4(gin,o3,*(const float4*)&wn_s[j*20+12]);
            float ae = baj;
            acc4(ae,o0,*(const float4*)&wap_s[j*20+ 0]);
            acc4(ae,o1,*(const float4*)&wap_s[j*20+ 4]);
            acc4(ae,o2,*(const float4*)&wap_s[j*20+ 8]);
            acc4(ae,o3,*(const float4*)&wap_s[j*20+12]);
            float rg = 1.f/(1.f+__expf(-(sr+bcrt)));
            float zg = 1.f/(1.f+__expf(-(sz+bczt)));
            float nx = fmaf(rg, sn + bhn, gin);
            float e2 = __expf(2.f*nx);
            float ng = 1.f - 2.f/(e2+1.f);          // tanh(nx)
            float hold = rb[hoff_j];
            float hn = fmaf(zg, hold-ng, ng);       // (1-z)n + z*h
            hnxt[r*GP_ROW + hoff_j] = hn;           // other buffer: safe pre-barrier
            air_s[r*132 + j] = hn + ae;
            if (s==63) out[(size_t)N_ + (size_t)(row0+r)*128 + j] = hn;
        }
        __syncthreads();   // bar_1: hcur reads done; hnxt h-region + air_s written

        // ---- coalesced air write + commit prefetched obs(s+1) into hnxt slack ----
        {
            int rr = t>>5, c0 = (t&31)*4;
            float4 av = *(const float4*)&air_s[rr*132 + c0];
            *(float4*)&air[((size_t)(row0+rr)*64 + s)*128 + c0] = av;
        }
        if (t < 256){
            int rr = t>>4, c = t&15;
            hnxt[rr*GP_ROW + (c>>2)*GP_CH + 32 + (c&3)] = obs_pf;
        }
        __syncthreads();   // bar_2: hnxt complete
    }
}

// ---------------- Kernel B: fused attention + MLP head ----------------
// Phase 1 (attn) uses wa/wb = wqp/wo; phase 2 (mlp) overwrites wa/wb = w0/w1
// so only 64 weight floats are persistent at a time.
__global__ __launch_bounds__(512) __attribute__((amdgpu_waves_per_eu(2, 4)))
void attnmlp_kernel(
    const float* __restrict__ obs, const float* __restrict__ wo,
    const float* __restrict__ bo,  const float* __restrict__ ws,
    const float* __restrict__ w0, const float* __restrict__ b0,
    const float* __restrict__ w1, const float* __restrict__ b1,
    const float* __restrict__ fcw, const float* __restrict__ fcb,
    const float* __restrict__ air, float* __restrict__ out)
{
    __shared__ float X_s[16*AP];
    __shared__ float ctx_s[16*AP];     // ctx, later h1
    __shared__ float comb_s[16*AP];
    __shared__ float obs_m[16][8];
    __shared__ float part[16][2][8];
    __shared__ float attn_s[16][4][2];
    __shared__ float mu_s[16], rs_s[16];
    __shared__ float kmu_s[16][2], krs_s[16][2];
    __shared__ int   kmask_s[16][2];
    __shared__ int   bothm_s[16];

    const int t = threadIdx.x;
    const int j = t>>2, kc = t&3;
    const int w = t>>6;
    const int n0 = blockIdx.x*16;
    const int jaddr_off = (j>>5)*40 + (j&31);

    // phase-1 weights
    const float4* wqp4 = (const float4*)(ws + WS_WQP);
    const float4* wo4g = (const float4*)wo;
    float4 wa4[8], wb4[8];
    #pragma unroll
    for (int i=0;i<8;i++){ wa4[i] = wqp4[j*32 + kc*8 + i]; wb4[i] = wo4g[j*32 + kc*8 + i]; }
    const float sqj = ws[WS_SQ+j], eqj = ws[WS_EQ+j];
    const float4 kcj = ((const float4*)(ws+WS_KC))[j];
    const float ek1j = ws[WS_EK1+j], skj = ws[WS_SK+j], ek2j = ws[WS_EK2+j];
    const float4 vcj = ((const float4*)(ws+WS_VC))[j];
    const float vbj = ws[WS_VB+j];
    const float boj = bo[j];
    const float b0j = b0[j], b1j = b1[j], fcj = fcw[j];

    // stage X tile + LN stats + missile staging/stats
    {
        int rr = t>>5, c0 = (t&31)*4;
        float4 xv = *(const float4*)&air[(size_t)(n0+rr)*128 + c0];
        *(float4*)&X_s[caddr(rr,c0)] = xv;
        float sm = xv.x+xv.y+xv.z+xv.w;
        float s2 = fmaf(xv.x,xv.x, fmaf(xv.y,xv.y, fmaf(xv.z,xv.z, xv.w*xv.w)));
        #pragma unroll
        for (int m=1;m<32;m<<=1){ sm += __shfl_xor(sm,m); s2 += __shfl_xor(s2,m); }
        if ((t&31)==0){
            float mu = sm*(1.f/128.f);
            float var = s2*(1.f/128.f) - mu*mu;
            mu_s[rr]=mu; rs_s[rr]=rsqrtf(var+1e-5f);
        }
    }
    if (t>=128 && t<256){
        int idx = t-128; int rr = idx>>3, f = idx&7;
        obs_m[rr][f] = obs[(size_t)(n0+rr)*15 + f];
    }
    if (t<32){
        int rr = t&15, mi = t>>4;
        const float* mp = &obs[(size_t)(n0+rr)*15 + mi*4];
        float m0=mp[0], m1=mp[1], m2=mp[2], m3=mp[3];
        const float tol1 = 1e-8f + 1e-5f, tol0 = 1e-8f;
        kmask_s[rr][mi] = (fabsf(m0-1.f)<=tol1)&&(fabsf(m1)<=tol0)&&
                          (fabsf(m2-1.f)<=tol1)&&(fabsf(m3)<=tol0);
        float mv[4]={m0,m1,m2,m3};
        float mu = ws[WS_MBC];
        #pragma unroll
        for (int f=0;f<4;f++) mu = fmaf(ws[WS_MV+f], mv[f], mu);
        float e2 = ws[WS_C0];
        #pragma unroll
        for (int a4=0;a4<4;a4++){
            e2 = fmaf(ws[WS_QLIN+a4], mv[a4], e2);
            #pragma unroll
            for (int b4=0;b4<4;b4++) e2 = fmaf(ws[WS_QQ+a4*4+b4]*mv[a4], mv[b4], e2);
        }
        float var = e2 - mu*mu;
        kmu_s[rr][mi]=mu; krs_s[rr][mi]=rsqrtf(var+1e-5f);
    }
    __syncthreads();

    // q matvec (folded LN): kc-butterfly, owner keeps rows 4kc..4kc+3
    float qown[4];
    #pragma unroll
    for (int r=0;r<16;r++){
        float acc = 0.f;
        const float* xb = &X_s[r*AP + kc*40];
        #pragma unroll
        for (int i=0;i<8;i++) acc4(acc, *(const float4*)&xb[i*4], wa4[i]);
        acc += __shfl_xor(acc,1); acc += __shfl_xor(acc,2);
        if (kc == (r>>2)) qown[r&3] = acc;
    }
    // scores
    #pragma unroll
    for (int oi=0;oi<4;oi++){
        int r = kc*4 + oi;
        float qv = fmaf(rs_s[r], qown[oi] - mu_s[r]*sqj, eqj);
        float4 m0v = *(const float4*)&obs_m[r][0];
        float4 m1v = *(const float4*)&obs_m[r][4];
        float k0 = fmaf(krs_s[r][0], dot4(kcj,m0v)+ek1j - kmu_s[r][0]*skj, ek2j);
        float k1 = fmaf(krs_s[r][1], dot4(kcj,m1v)+ek1j - kmu_s[r][1]*skj, ek2j);
        float p0 = qv*k0, p1 = qv*k1;
        #pragma unroll
        for (int m=4;m<64;m<<=1){ p0 += __shfl_xor(p0,m); p1 += __shfl_xor(p1,m); }
        if ((t&63)==kc){ part[r][0][w]=p0; part[r][1][w]=p1; }
    }
    __syncthreads();
    if (t<64){
        int rr = t&15, hd = t>>4;
        float s0 = part[rr][0][2*hd] + part[rr][0][2*hd+1];
        float s1 = part[rr][1][2*hd] + part[rr][1][2*hd+1];
        const float scale = 0.17677669529663687f;  // 1/sqrt(32)
        s0 *= scale; s1 *= scale;
        int m0 = kmask_s[rr][0], m1 = kmask_s[rr][1];
        float a0, a1;
        if (m0 && m1) { a0=0.f; a1=0.f; if (hd==0) bothm_s[rr]=1; }
        else {
            if (hd==0) bothm_s[rr]=0;
            if (m0)      { a0=0.f; a1=1.f; }
            else if (m1) { a0=1.f; a1=0.f; }
            else {
                float mx = fmaxf(s0,s1);
                float e0 = __expf(s0-mx), e1 = __expf(s1-mx);
                float inv = 1.f/(e0+e1);
                a0 = e0*inv; a1 = e1*inv;
            }
        }
        attn_s[rr][hd][0]=a0; attn_s[rr][hd][1]=a1;
    }
    __syncthreads();
    // ctx (v on the fly)
    {
        int hd = j>>5;
        #pragma unroll
        for (int oi=0;oi<4;oi++){
            int r = kc*4 + oi;
            float4 m0v = *(const float4*)&obs_m[r][0];
            float4 m1v = *(const float4*)&obs_m[r][4];
            float v0 = dot4(vcj,m0v)+vbj, v1 = dot4(vcj,m1v)+vbj;
            ctx_s[r*AP + jaddr_off] = attn_s[r][hd][0]*v0 + attn_s[r][hd][1]*v1;
        }
    }
    __syncthreads();
    // attn_out matvec + nan guard + residual -> comb_s
    {
        float aown[4];
        #pragma unroll
        for (int r=0;r<16;r++){
            float acc = 0.f;
            const float* zb = &ctx_s[r*AP + kc*40];
            #pragma unroll
            for (int i=0;i<8;i++) acc4(acc, *(const float4*)&zb[i*4], wb4[i]);
            acc += __shfl_xor(acc,1); acc += __shfl_xor(acc,2);
            if (kc == (r>>2)) aown[r&3] = acc;
        }
        #pragma unroll
        for (int oi=0;oi<4;oi++){
            int r = kc*4 + oi;
            float ao = bothm_s[r] ? 0.f : (aown[oi] + boj);
            comb_s[r*AP + jaddr_off] = X_s[r*AP + jaddr_off] + ao;
        }
    }
    // ---- phase 2: reload weight regs with mlp weights ----
    {
        const float4* w04g = (const float4*)w0;
        const float4* w14g = (const float4*)w1;
        #pragma unroll
        for (int i=0;i<8;i++){ wa4[i] = w04g[j*32 + kc*8 + i]; wb4[i] = w14g[j*32 + kc*8 + i]; }
    }
    __syncthreads();   // comb_s complete; ctx_s reads done (reused as H below)
    // mlp0 -> ctx_s (reused as h1)
    {
        float hown[4];
        #pragma unroll
        for (int r=0;r<16;r++){
            float acc = 0.f;
            const float* cb = &comb_s[r*AP + kc*40];
            #pragma unroll
            for (int i=0;i<8;i++) acc4(acc, *(const float4*)&cb[i*4], wa4[i]);
            acc += __shfl_xor(acc,1); acc += __shfl_xor(acc,2);
            if (kc == (r>>2)){
                float v = acc + b0j;
                hown[r&3] = (v > 0.f) ? v : 0.01f*v;
            }
        }
        #pragma unroll
        for (int oi=0;oi<4;oi++) ctx_s[(kc*4+oi)*AP + jaddr_off] = hown[oi];
    }
    __syncthreads();
    // mlp1 + leaky + fco partial
    {
        float pown[4];
        #pragma unroll
        for (int r=0;r<16;r++){
            float acc = 0.f;
            const float* hb = &ctx_s[r*AP + kc*40];
            #pragma unroll
            for (int i=0;i<8;i++) acc4(acc, *(const float4*)&hb[i*4], wb4[i]);
            acc += __shfl_xor(acc,1); acc += __shfl_xor(acc,2);
            if (kc == (r>>2)){
                float v = acc + b1j;
                v = (v > 0.f) ? v : 0.01f*v;
                pown[r&3] = v * fcj;
            }
        }
        #pragma unroll
        for (int oi=0;oi<4;oi++){
            float p = pown[oi];
            #pragma unroll
            for (int m=4;m<64;m<<=1) p += __shfl_xor(p,m);
            if ((t&63)==kc) part[kc*4+oi][0][w] = p;
        }
    }
    __syncthreads();
    if (t<16){
        float a = 0.f;
        #pragma unroll
        for (int k=0;k<8;k++) a += part[t][0][k];
        out[n0 + t] = a + fcb[0];
    }
}

extern "C" void kernel_launch(void* const* d_in, const int* in_sizes, int n_in,
                              void* d_out, int out_size, void* d_ws, size_t ws_size,
                              hipStream_t stream) {
    const float* obs       = (const float*)d_in[0];
    const float* h0        = (const float*)d_in[1];
    const float* enc_air_w = (const float*)d_in[2];
    const float* enc_air_b = (const float*)d_in[3];
    const float* enc_m_w   = (const float*)d_in[4];
    const float* enc_m_b   = (const float*)d_in[5];
    const float* gru_wih   = (const float*)d_in[6];
    const float* gru_whh   = (const float*)d_in[7];
    const float* gru_bih   = (const float*)d_in[8];
    const float* gru_bhh   = (const float*)d_in[9];
    const float* qln_w     = (const float*)d_in[10];
    const float* qln_b     = (const float*)d_in[11];
    const float* kln_w     = (const float*)d_in[12];
    const float* kln_b     = (const float*)d_in[13];
    const float* attn_in_w = (const float*)d_in[14];
    const float* attn_in_b = (const float*)d_in[15];
    const float* attn_out_w= (const float*)d_in[16];
    const float* attn_out_b= (const float*)d_in[17];
    const float* mlp0_w    = (const float*)d_in[18];
    const float* mlp0_b    = (const float*)d_in[19];
    const float* mlp1_w    = (const float*)d_in[20];
    const float* mlp1_b    = (const float*)d_in[21];
    const float* fco_w     = (const float*)d_in[22];
    const float* fco_b     = (const float*)d_in[23];
    float* out = (float*)d_out;
    float* ws  = (float*)d_ws;
    float* air = ws + WS_AIR;

    precompute_kernel<<<dim3(105), dim3(256), 0, stream>>>(
        enc_air_w, enc_air_b, enc_m_w, enc_m_b, gru_wih, gru_bih,
        qln_w, qln_b, kln_w, kln_b, attn_in_w, attn_in_b, ws);

    gru_kernel<<<dim3(256), dim3(512), 0, stream>>>(
        obs, h0, gru_whh, gru_bhh, enc_air_b, ws, air, out);

    attnmlp_kernel<<<dim3(N_/16), dim3(512), 0, stream>>>(
        obs, attn_out_w, attn_out_b, ws,
        mlp0_w, mlp0_b, mlp1_w, mlp1_b, fco_w, fco_b,
        air, out);
}

// Round 8
// 2376.958 us; speedup vs baseline: 2.9439x; 2.9439x over previous
//
#include <hip/hip_runtime.h>
#include <math.h>

#define B_   4096
#define S_   64
#define H_   128
#define N_   (B_*S_)

// ---- workspace float offsets ----
#define WS_WC    0        // [384][16]  combined obs->gi weights (padded f=16)
#define WS_BC    6144     // [384]      combined gi bias
#define WS_WAP   6528     // [128][16]  padded enc_air_w
#define WS_WQP   8576     // [128][128] wq * qln_w (folded)
#define WS_SQ    24960    // [128] row sums of wqp
#define WS_EQ    25088    // [128] wq@qln_b + bq
#define WS_KC    25216    // [128][4]  (wk*klnw)@enc_m_w
#define WS_EK1   25728    // [128] (wk*klnw)@enc_m_b
#define WS_SK    25856    // [128] rowsum(wk*klnw)
#define WS_EK2   25984    // [128] wk@kln_b + bk
#define WS_VC    26112    // [128][4]  wv@enc_m_w
#define WS_VB    26624    // [128] wv@enc_m_b + bv
#define WS_MV    26752    // [4] mean weights for keys_raw mean
#define WS_QQ    26756    // [16] 4x4 quadratic form for E[y^2]
#define WS_QLIN  26772    // [4]
#define WS_MBC   26776
#define WS_C0    26777
#define WS_AIR   27392    // [N_][128] air_feat buffer

#define AP 172   // attn row pitch

__device__ __forceinline__ float dot4(float4 a, float4 b){
    return fmaf(a.x,b.x, fmaf(a.y,b.y, fmaf(a.z,b.z, a.w*b.w)));
}
__device__ __forceinline__ void acc4(float& acc, float4 a, float4 b){
    acc = fmaf(a.x,b.x,acc); acc = fmaf(a.y,b.y,acc);
    acc = fmaf(a.z,b.z,acc); acc = fmaf(a.w,b.w,acc);
}
__device__ __forceinline__ int caddr(int r, int c){       // attn chunked layout
    return r*AP + (c>>5)*40 + (c&31);
}

// ---------------- precompute folded weights ----------------
__global__ void precompute_kernel(
    const float* __restrict__ enc_air_w, const float* __restrict__ enc_air_b,
    const float* __restrict__ enc_m_w,  const float* __restrict__ enc_m_b,
    const float* __restrict__ gru_wih,  const float* __restrict__ gru_bih,
    const float* __restrict__ qln_w, const float* __restrict__ qln_b,
    const float* __restrict__ kln_w, const float* __restrict__ kln_b,
    const float* __restrict__ attn_in_w, const float* __restrict__ attn_in_b,
    float* __restrict__ ws)
{
    int i = blockIdx.x*blockDim.x + threadIdx.x;
    if (i < 6144) {                       // Wc[o][f] = sum_k wih[o][k]*Wa[k][f]
        int o = i>>4, f = i&15; float a = 0.f;
        if (f < 15) for (int k=0;k<128;k++) a = fmaf(gru_wih[o*128+k], enc_air_w[k*15+f], a);
        ws[WS_WC+i] = a;
    } else if (i < 6528) {                // bc
        int o = i-6144; float a = gru_bih[o];
        for (int k=0;k<128;k++) a = fmaf(gru_wih[o*128+k], enc_air_b[k], a);
        ws[WS_BC+o] = a;
    } else if (i < 8576) {                // Wap padded
        int idx = i-6528; int j = idx>>4, f = idx&15;
        ws[WS_WAP+idx] = (f<15) ? enc_air_w[j*15+f] : 0.f;
    } else if (i < 24960) {               // wqp
        int idx = i-8576; int o = idx>>7, j = idx&127;
        ws[WS_WQP+idx] = attn_in_w[o*128+j]*qln_w[j];
    } else if (i < 25088) {               // sq
        int o = i-24960; float a=0.f;
        for (int j=0;j<128;j++) a = fmaf(attn_in_w[o*128+j], qln_w[j], a);
        ws[WS_SQ+o]=a;
    } else if (i < 25216) {               // eq
        int o = i-25088; float a = attn_in_b[o];
        for (int j=0;j<128;j++) a = fmaf(attn_in_w[o*128+j], qln_b[j], a);
        ws[WS_EQ+o]=a;
    } else if (i < 25728) {               // Kc
        int idx = i-25216; int o = idx>>2, f = idx&3; float a=0.f;
        for (int j=0;j<128;j++) a = fmaf(attn_in_w[(128+o)*128+j]*kln_w[j], enc_m_w[j*4+f], a);
        ws[WS_KC+idx]=a;
    } else if (i < 25856) {               // ek1
        int o = i-25728; float a=0.f;
        for (int j=0;j<128;j++) a = fmaf(attn_in_w[(128+o)*128+j]*kln_w[j], enc_m_b[j], a);
        ws[WS_EK1+o]=a;
    } else if (i < 25984) {               // sk
        int o = i-25856; float a=0.f;
        for (int j=0;j<128;j++) a = fmaf(attn_in_w[(128+o)*128+j], kln_w[j], a);
        ws[WS_SK+o]=a;
    } else if (i < 26112) {               // ek2
        int o = i-25984; float a = attn_in_b[128+o];
        for (int j=0;j<128;j++) a = fmaf(attn_in_w[(128+o)*128+j], kln_b[j], a);
        ws[WS_EK2+o]=a;
    } else if (i < 26624) {               // Vc
        int idx = i-26112; int o = idx>>2, f = idx&3; float a=0.f;
        for (int j=0;j<128;j++) a = fmaf(attn_in_w[(256+o)*128+j], enc_m_w[j*4+f], a);
        ws[WS_VC+idx]=a;
    } else if (i < 26752) {               // vb
        int o = i-26624; float a = attn_in_b[256+o];
        for (int j=0;j<128;j++) a = fmaf(attn_in_w[(256+o)*128+j], enc_m_b[j], a);
        ws[WS_VB+o]=a;
    } else if (i < 26756) {               // Mv
        int f = i-26752; float a=0.f;
        for (int j=0;j<128;j++) a += enc_m_w[j*4+f];
        ws[WS_MV+f]=a*(1.f/128.f);
    } else if (i < 26772) {               // QQ
        int idx = i-26756; int a4 = idx>>2, b4 = idx&3; float a=0.f;
        for (int j=0;j<128;j++) a = fmaf(enc_m_w[j*4+a4], enc_m_w[j*4+b4], a);
        ws[WS_QQ+idx]=a*(1.f/128.f);
    } else if (i < 26776) {               // qlin
        int f = i-26772; float a=0.f;
        for (int j=0;j<128;j++) a = fmaf(enc_m_b[j], enc_m_w[j*4+f], a);
        ws[WS_QLIN+f]=a*(2.f/128.f);
    } else if (i == 26776) {
        float a=0.f; for (int j=0;j<128;j++) a += enc_m_b[j];
        ws[WS_MBC]=a*(1.f/128.f);
    } else if (i == 26777) {
        float a=0.f; for (int j=0;j<128;j++) a = fmaf(enc_m_b[j], enc_m_b[j], a);
        ws[WS_C0]=a*(1.f/128.f);
    }
}

// ---------------- Kernel A: GRU ----------------
// 256 blocks x 16 rows x 1024 threads. Thread (j=t>>3, kc=t&7):
//   registers: whh r/z 16-float chunks (32 f) + 2 obs-fold f/gate (4 f) + biases.
//   LDS: whh n-gate block (wnh_s, re-read 4xfloat4/step), Wc_n/Wap rows, h dbuf.
// Register diet targets <=80 live so even a 64-cap only grazes; flat_wgs(1024)
// + waves_per_eu(4,4) (min=max=launchability bound) requests the 128 budget.
__global__ __attribute__((amdgpu_flat_work_group_size(1024,1024), amdgpu_waves_per_eu(4,4)))
void gru_kernel(
    const float* __restrict__ obs, const float* __restrict__ h0,
    const float* __restrict__ whh, const float* __restrict__ bhh,
    const float* __restrict__ ba,  const float* __restrict__ ws,
    float* __restrict__ air, float* __restrict__ out)
{
    __shared__ float h_s[2][16*164];   // chunk pitch 20 (banks 20kc%32 distinct), row pitch 164
    __shared__ float obs_s[16*20];     // row pitch 20
    __shared__ float air_s[16*132];
    __shared__ float wcn_s[128*20];    // Wc_n rows (obs->n fold), pitch 20
    __shared__ float wap_s[128*20];    // Wap rows, pitch 20
    __shared__ float wnh_s[128*132];   // whh n-gate rows, pitch 132

    const int t  = threadIdx.x;
    const int j  = t>>3;        // 0..127 output column
    const int kc = t&7;         // 0..7 k-chunk (16 floats)
    const int row0 = blockIdx.x*16;

    // --- persistent weights: 32 + 4 floats ---
    const float4* whh4 = (const float4*)whh;
    float4 whr[4], whz[4];
    #pragma unroll
    for (int i=0;i<4;i++){
        whr[i] = whh4[(      j)*32 + kc*4 + i];
        whz[i] = whh4[(128 + j)*32 + kc*4 + i];
    }
    const float wro0 = ws[WS_WC + j*16 + 2*kc];
    const float wro1 = ws[WS_WC + j*16 + 2*kc+1];
    const float wzo0 = ws[WS_WC + (128+j)*16 + 2*kc];
    const float wzo1 = ws[WS_WC + (128+j)*16 + 2*kc+1];
    const float bcrt = ws[WS_BC+j]     + bhh[j];
    const float bczt = ws[WS_BC+128+j] + bhh[128+j];
    const float bcn  = ws[WS_BC+256+j];
    const float bhn  = bhh[256+j];
    const float baj  = ba[j];
    const int hoff_j = (j>>4)*20 + (j&15);

    // --- stage whh n-gate rows into LDS (4096 float4 by 1024 threads) ---
    #pragma unroll
    for (int it=0; it<4; it++){
        int idx = t + 1024*it;            // 0..4095
        int jr = idx>>5, c4 = idx&31;
        *(float4*)&wnh_s[jr*132 + c4*4] = whh4[(256+jr)*32 + c4];
    }
    // --- stage Wc_n / Wap into LDS ---
    {
        int f = t&15, jr = t>>4;   // jr 0..63
        wcn_s[jr*20+f]      = ws[WS_WC + (256+jr)*16 + f];
        wcn_s[(jr+64)*20+f] = ws[WS_WC + (256+jr+64)*16 + f];
        wap_s[jr*20+f]      = ws[WS_WAP + jr*16 + f];
        wap_s[(jr+64)*20+f] = ws[WS_WAP + (jr+64)*16 + f];
    }
    // --- stage h0 + obs(0) ---
    if (t < 512){
        int rr = t>>5, c0 = (t&31)*4;
        float4 hv = *(const float4*)&h0[(size_t)(row0+rr)*128 + c0];
        *(float4*)&h_s[0][rr*164 + (c0>>4)*20 + (c0&15)] = hv;
    }
    if (t < 256){
        int rr = t>>4, c = t&15;
        obs_s[rr*20+c] = (c<15) ? obs[((size_t)(row0+rr)*64 + 0)*15 + c] : 0.f;
    }
    __syncthreads();

    for (int s=0;s<64;s++){
        const float* hcur = h_s[s&1];
        float*       hnxt = h_s[(s+1)&1];

        // prefetch obs(s+1) into a register (overlaps the dot phase)
        float obs_pf = 0.f;
        if (t < 256){
            int rr = t>>4, c = t&15;
            int sn = (s<63) ? s+1 : s;
            obs_pf = (c<15) ? obs[((size_t)(row0+rr)*64 + sn)*15 + c] : 0.f;
        }

        float sAr=0.f,sAz=0.f,sAn=0.f, sBr=0.f,sBz=0.f,sBn=0.f;
        #pragma unroll
        for (int p=0;p<8;p++){
            const int r0=2*p, r1=2*p+1;
            // n-gate weights from LDS (short-lived; re-read each pair)
            float4 wn0 = *(const float4*)&wnh_s[j*132 + kc*16 +  0];
            float4 wn1 = *(const float4*)&wnh_s[j*132 + kc*16 +  4];
            float4 wn2 = *(const float4*)&wnh_s[j*132 + kc*16 +  8];
            float4 wn3 = *(const float4*)&wnh_s[j*132 + kc*16 + 12];
            float pr0=0.f,pz0=0.f,pn0=0.f, pr1=0.f,pz1=0.f,pn1=0.f;
            {
                const float* hb = &hcur[r0*164 + kc*20];
                float4 h0v = *(const float4*)&hb[0];
                float4 h1v = *(const float4*)&hb[4];
                float4 h2v = *(const float4*)&hb[8];
                float4 h3v = *(const float4*)&hb[12];
                acc4(pr0,h0v,whr[0]); acc4(pz0,h0v,whz[0]); acc4(pn0,h0v,wn0);
                acc4(pr0,h1v,whr[1]); acc4(pz0,h1v,whz[1]); acc4(pn0,h1v,wn1);
                acc4(pr0,h2v,whr[2]); acc4(pz0,h2v,whz[2]); acc4(pn0,h2v,wn2);
                acc4(pr0,h3v,whr[3]); acc4(pz0,h3v,whz[3]); acc4(pn0,h3v,wn3);
                float o0 = obs_s[r0*20+2*kc], o1 = obs_s[r0*20+2*kc+1];
                pr0 = fmaf(o0,wro0, fmaf(o1,wro1, pr0));
                pz0 = fmaf(o0,wzo0, fmaf(o1,wzo1, pz0));
            }
            {
                const float* hb = &hcur[r1*164 + kc*20];
                float4 h0v = *(const float4*)&hb[0];
                float4 h1v = *(const float4*)&hb[4];
                float4 h2v = *(const float4*)&hb[8];
                float4 h3v = *(const float4*)&hb[12];
                acc4(pr1,h0v,whr[0]); acc4(pz1,h0v,whz[0]); acc4(pn1,h0v,wn0);
                acc4(pr1,h1v,whr[1]); acc4(pz1,h1v,whz[1]); acc4(pn1,h1v,wn1);
                acc4(pr1,h2v,whr[2]); acc4(pz1,h2v,whz[2]); acc4(pn1,h2v,wn2);
                acc4(pr1,h3v,whr[3]); acc4(pz1,h3v,whz[3]); acc4(pn1,h3v,wn3);
                float o0 = obs_s[r1*20+2*kc], o1 = obs_s[r1*20+2*kc+1];
                pr1 = fmaf(o0,wro0, fmaf(o1,wro1, pr1));
                pz1 = fmaf(o0,wzo0, fmaf(o1,wzo1, pz1));
            }
            // reduce over kc octet (lanes differ in bits 0..2)
            pr0 += __shfl_xor(pr0,1); pr0 += __shfl_xor(pr0,2); pr0 += __shfl_xor(pr0,4);
            pz0 += __shfl_xor(pz0,1); pz0 += __shfl_xor(pz0,2); pz0 += __shfl_xor(pz0,4);
            pn0 += __shfl_xor(pn0,1); pn0 += __shfl_xor(pn0,2); pn0 += __shfl_xor(pn0,4);
            pr1 += __shfl_xor(pr1,1); pr1 += __shfl_xor(pr1,2); pr1 += __shfl_xor(pr1,4);
            pz1 += __shfl_xor(pz1,1); pz1 += __shfl_xor(pz1,2); pz1 += __shfl_xor(pz1,4);
            pn1 += __shfl_xor(pn1,1); pn1 += __shfl_xor(pn1,2); pn1 += __shfl_xor(pn1,4);
            // latch: lane kc keeps rows {kc, kc+8}
            if ((r0&7)==kc){ if (r0<8){sAr=pr0;sAz=pz0;sAn=pn0;} else {sBr=pr0;sBz=pz0;sBn=pn0;} }
            if ((r1&7)==kc){ if (r1<8){sAr=pr1;sAz=pz1;sAn=pn1;} else {sBr=pr1;sBz=pz1;sBn=pn1;} }
        }

        // ---- finalize rows kc and kc+8 (all lanes in parallel) ----
        #pragma unroll
        for (int u=0;u<2;u++){
            const int r = kc + 8*u;
            float sr = u ? sBr : sAr;
            float sz = u ? sBz : sAz;
            float sn = u ? sBn : sAn;
            const float* ob = &obs_s[r*20];
            float4 o0 = *(const float4*)&ob[0],  o1 = *(const float4*)&ob[4];
            float4 o2 = *(const float4*)&ob[8],  o3 = *(const float4*)&ob[12];
            float gin = bcn;
            acc4(gin,o0,*(const float4*)&wcn_s[j*20+ 0]);
            acc4(gin,o1,*(const float4*)&wcn_s[j*20+ 4]);
            acc4(gin,o2,*(const float4*)&wcn_s[j*20+ 8]);
            acc4(gin,o3,*(const float4*)&wcn_s[j*20+12]);
            float ae = baj;
            acc4(ae,o0,*(const float4*)&wap_s[j*20+ 0]);
            acc4(ae,o1,*(const float4*)&wap_s[j*20+ 4]);
            acc4(ae,o2,*(const float4*)&wap_s[j*20+ 8]);
            acc4(ae,o3,*(const float4*)&wap_s[j*20+12]);
            float rg = 1.f/(1.f+__expf(-(sr+bcrt)));
            float zg = 1.f/(1.f+__expf(-(sz+bczt)));
            float nx = fmaf(rg, sn + bhn, gin);
            float e2 = __expf(2.f*nx);
            float ng = 1.f - 2.f/(e2+1.f);          // tanh(nx)
            float hold = hcur[r*164 + hoff_j];
            float hn = fmaf(zg, hold-ng, ng);       // (1-z)n + z*h
            hnxt[r*164 + hoff_j] = hn;
            air_s[r*132 + j] = hn + ae;
            if (s==63) out[(size_t)N_ + (size_t)(row0+r)*128 + j] = hn;
        }
        __syncthreads();   // bar_1: hcur/obs reads done; hnxt/air_s written

        // ---- coalesced air write + commit prefetched obs(s+1) ----
        if (t < 512){
            int rr = t>>5, c0 = (t&31)*4;
            float4 av = *(const float4*)&air_s[rr*132 + c0];
            *(float4*)&air[((size_t)(row0+rr)*64 + s)*128 + c0] = av;
        }
        if (t < 256){
            int rr = t>>4, c = t&15;
            obs_s[rr*20+c] = obs_pf;
        }
        __syncthreads();   // bar_2
    }
}

// ---------------- Kernel B: fused attention + MLP head ----------------
__global__ __launch_bounds__(512) __attribute__((amdgpu_waves_per_eu(2, 4)))
void attnmlp_kernel(
    const float* __restrict__ obs, const float* __restrict__ wo,
    const float* __restrict__ bo,  const float* __restrict__ ws,
    const float* __restrict__ w0, const float* __restrict__ b0,
    const float* __restrict__ w1, const float* __restrict__ b1,
    const float* __restrict__ fcw, const float* __restrict__ fcb,
    const float* __restrict__ air, float* __restrict__ out)
{
    __shared__ float X_s[16*AP];
    __shared__ float ctx_s[16*AP];     // ctx, later h1
    __shared__ float comb_s[16*AP];
    __shared__ float obs_m[16][8];
    __shared__ float part[16][2][8];
    __shared__ float attn_s[16][4][2];
    __shared__ float mu_s[16], rs_s[16];
    __shared__ float kmu_s[16][2], krs_s[16][2];
    __shared__ int   kmask_s[16][2];
    __shared__ int   bothm_s[16];

    const int t = threadIdx.x;
    const int j = t>>2, kc = t&3;
    const int w = t>>6;
    const int n0 = blockIdx.x*16;
    const int jaddr_off = (j>>5)*40 + (j&31);

    // phase-1 weights
    const float4* wqp4 = (const float4*)(ws + WS_WQP);
    const float4* wo4g = (const float4*)wo;
    float4 wa4[8], wb4[8];
    #pragma unroll
    for (int i=0;i<8;i++){ wa4[i] = wqp4[j*32 + kc*8 + i]; wb4[i] = wo4g[j*32 + kc*8 + i]; }
    const float sqj = ws[WS_SQ+j], eqj = ws[WS_EQ+j];
    const float4 kcj = ((const float4*)(ws+WS_KC))[j];
    const float ek1j = ws[WS_EK1+j], skj = ws[WS_SK+j], ek2j = ws[WS_EK2+j];
    const float4 vcj = ((const float4*)(ws+WS_VC))[j];
    const float vbj = ws[WS_VB+j];
    const float boj = bo[j];
    const float b0j = b0[j], b1j = b1[j], fcj = fcw[j];

    // stage X tile + LN stats + missile staging/stats
    {
        int rr = t>>5, c0 = (t&31)*4;
        float4 xv = *(const float4*)&air[(size_t)(n0+rr)*128 + c0];
        *(float4*)&X_s[caddr(rr,c0)] = xv;
        float sm = xv.x+xv.y+xv.z+xv.w;
        float s2 = fmaf(xv.x,xv.x, fmaf(xv.y,xv.y, fmaf(xv.z,xv.z, xv.w*xv.w)));
        #pragma unroll
        for (int m=1;m<32;m<<=1){ sm += __shfl_xor(sm,m); s2 += __shfl_xor(s2,m); }
        if ((t&31)==0){
            float mu = sm*(1.f/128.f);
            float var = s2*(1.f/128.f) - mu*mu;
            mu_s[rr]=mu; rs_s[rr]=rsqrtf(var+1e-5f);
        }
    }
    if (t>=128 && t<256){
        int idx = t-128; int rr = idx>>3, f = idx&7;
        obs_m[rr][f] = obs[(size_t)(n0+rr)*15 + f];
    }
    if (t<32){
        int rr = t&15, mi = t>>4;
        const float* mp = &obs[(size_t)(n0+rr)*15 + mi*4];
        float m0=mp[0], m1=mp[1], m2=mp[2], m3=mp[3];
        const float tol1 = 1e-8f + 1e-5f, tol0 = 1e-8f;
        kmask_s[rr][mi] = (fabsf(m0-1.f)<=tol1)&&(fabsf(m1)<=tol0)&&
                          (fabsf(m2-1.f)<=tol1)&&(fabsf(m3)<=tol0);
        float mv[4]={m0,m1,m2,m3};
        float mu = ws[WS_MBC];
        #pragma unroll
        for (int f=0;f<4;f++) mu = fmaf(ws[WS_MV+f], mv[f], mu);
        float e2 = ws[WS_C0];
        #pragma unroll
        for (int a4=0;a4<4;a4++){
            e2 = fmaf(ws[WS_QLIN+a4], mv[a4], e2);
            #pragma unroll
            for (int b4=0;b4<4;b4++) e2 = fmaf(ws[WS_QQ+a4*4+b4]*mv[a4], mv[b4], e2);
        }
        float var = e2 - mu*mu;
        kmu_s[rr][mi]=mu; krs_s[rr][mi]=rsqrtf(var+1e-5f);
    }
    __syncthreads();

    // q matvec (folded LN): kc-butterfly, owner keeps rows 4kc..4kc+3
    float qown[4];
    #pragma unroll
    for (int r=0;r<16;r++){
        float acc = 0.f;
        const float* xb = &X_s[r*AP + kc*40];
        #pragma unroll
        for (int i=0;i<8;i++) acc4(acc, *(const float4*)&xb[i*4], wa4[i]);
        acc += __shfl_xor(acc,1); acc += __shfl_xor(acc,2);
        if (kc == (r>>2)) qown[r&3] = acc;
    }
    // scores
    #pragma unroll
    for (int oi=0;oi<4;oi++){
        int r = kc*4 + oi;
        float qv = fmaf(rs_s[r], qown[oi] - mu_s[r]*sqj, eqj);
        float4 m0v = *(const float4*)&obs_m[r][0];
        float4 m1v = *(const float4*)&obs_m[r][4];
        float k0 = fmaf(krs_s[r][0], dot4(kcj,m0v)+ek1j - kmu_s[r][0]*skj, ek2j);
        float k1 = fmaf(krs_s[r][1], dot4(kcj,m1v)+ek1j - kmu_s[r][1]*skj, ek2j);
        float p0 = qv*k0, p1 = qv*k1;
        #pragma unroll
        for (int m=4;m<64;m<<=1){ p0 += __shfl_xor(p0,m); p1 += __shfl_xor(p1,m); }
        if ((t&63)==kc){ part[r][0][w]=p0; part[r][1][w]=p1; }
    }
    __syncthreads();
    if (t<64){
        int rr = t&15, hd = t>>4;
        float s0 = part[rr][0][2*hd] + part[rr][0][2*hd+1];
        float s1 = part[rr][1][2*hd] + part[rr][1][2*hd+1];
        const float scale = 0.17677669529663687f;  // 1/sqrt(32)
        s0 *= scale; s1 *= scale;
        int m0 = kmask_s[rr][0], m1 = kmask_s[rr][1];
        float a0, a1;
        if (m0 && m1) { a0=0.f; a1=0.f; if (hd==0) bothm_s[rr]=1; }
        else {
            if (hd==0) bothm_s[rr]=0;
            if (m0)      { a0=0.f; a1=1.f; }
            else if (m1) { a0=1.f; a1=0.f; }
            else {
                float mx = fmaxf(s0,s1);
                float e0 = __expf(s0-mx), e1 = __expf(s1-mx);
                float inv = 1.f/(e0+e1);
                a0 = e0*inv; a1 = e1*inv;
            }
        }
        attn_s[rr][hd][0]=a0; attn_s[rr][hd][1]=a1;
    }
    __syncthreads();
    // ctx (v on the fly)
    {
        int hd = j>>5;
        #pragma unroll
        for (int oi=0;oi<4;oi++){
            int r = kc*4 + oi;
            float4 m0v = *(const float4*)&obs_m[r][0];
            float4 m1v = *(const float4*)&obs_m[r][4];
            float v0 = dot4(vcj,m0v)+vbj, v1 = dot4(vcj,m1v)+vbj;
            ctx_s[r*AP + jaddr_off] = attn_s[r][hd][0]*v0 + attn_s[r][hd][1]*v1;
        }
    }
    __syncthreads();
    // attn_out matvec + nan guard + residual -> comb_s
    {
        float aown[4];
        #pragma unroll
        for (int r=0;r<16;r++){
            float acc = 0.f;
            const float* zb = &ctx_s[r*AP + kc*40];
            #pragma unroll
            for (int i=0;i<8;i++) acc4(acc, *(const float4*)&zb[i*4], wb4[i]);
            acc += __shfl_xor(acc,1); acc += __shfl_xor(acc,2);
            if (kc == (r>>2)) aown[r&3] = acc;
        }
        #pragma unroll
        for (int oi=0;oi<4;oi++){
            int r = kc*4 + oi;
            float ao = bothm_s[r] ? 0.f : (aown[oi] + boj);
            comb_s[r*AP + jaddr_off] = X_s[r*AP + jaddr_off] + ao;
        }
    }
    // ---- phase 2: reload weight regs with mlp weights ----
    {
        const float4* w04g = (const float4*)w0;
        const float4* w14g = (const float4*)w1;
        #pragma unroll
        for (int i=0;i<8;i++){ wa4[i] = w04g[j*32 + kc*8 + i]; wb4[i] = w14g[j*32 + kc*8 + i]; }
    }
    __syncthreads();   // comb_s complete; ctx_s reads done (reused as H below)
    // mlp0 -> ctx_s (reused as h1)
    {
        float hown[4];
        #pragma unroll
        for (int r=0;r<16;r++){
            float acc = 0.f;
            const float* cb = &comb_s[r*AP + kc*40];
            #pragma unroll
            for (int i=0;i<8;i++) acc4(acc, *(const float4*)&cb[i*4], wa4[i]);
            acc += __shfl_xor(acc,1); acc += __shfl_xor(acc,2);
            if (kc == (r>>2)){
                float v = acc + b0j;
                hown[r&3] = (v > 0.f) ? v : 0.01f*v;
            }
        }
        #pragma unroll
        for (int oi=0;oi<4;oi++) ctx_s[(kc*4+oi)*AP + jaddr_off] = hown[oi];
    }
    __syncthreads();
    // mlp1 + leaky + fco partial
    {
        float pown[4];
        #pragma unroll
        for (int r=0;r<16;r++){
            float acc = 0.f;
            const float* hb = &ctx_s[r*AP + kc*40];
            #pragma unroll
            for (int i=0;i<8;i++) acc4(acc, *(const float4*)&hb[i*4], wb4[i]);
            acc += __shfl_xor(acc,1); acc += __shfl_xor(acc,2);
            if (kc == (r>>2)){
                float v = acc + b1j;
                v = (v > 0.f) ? v : 0.01f*v;
                pown[r&3] = v * fcj;
            }
        }
        #pragma unroll
        for (int oi=0;oi<4;oi++){
            float p = pown[oi];
            #pragma unroll
            for (int m=4;m<64;m<<=1) p += __shfl_xor(p,m);
            if ((t&63)==kc) part[kc*4+oi][0][w] = p;
        }
    }
    __syncthreads();
    if (t<16){
        float a = 0.f;
        #pragma unroll
        for (int k=0;k<8;k++) a += part[t][0][k];
        out[n0 + t] = a + fcb[0];
    }
}

extern "C" void kernel_launch(void* const* d_in, const int* in_sizes, int n_in,
                              void* d_out, int out_size, void* d_ws, size_t ws_size,
                              hipStream_t stream) {
    const float* obs       = (const float*)d_in[0];
    const float* h0        = (const float*)d_in[1];
    const float* enc_air_w = (const float*)d_in[2];
    const float* enc_air_b = (const float*)d_in[3];
    const float* enc_m_w   = (const float*)d_in[4];
    const float* enc_m_b   = (const float*)d_in[5];
    const float* gru_wih   = (const float*)d_in[6];
    const float* gru_whh   = (const float*)d_in[7];
    const float* gru_bih   = (const float*)d_in[8];
    const float* gru_bhh   = (const float*)d_in[9];
    const float* qln_w     = (const float*)d_in[10];
    const float* qln_b     = (const float*)d_in[11];
    const float* kln_w     = (const float*)d_in[12];
    const float* kln_b     = (const float*)d_in[13];
    const float* attn_in_w = (const float*)d_in[14];
    const float* attn_in_b = (const float*)d_in[15];
    const float* attn_out_w= (const float*)d_in[16];
    const float* attn_out_b= (const float*)d_in[17];
    const float* mlp0_w    = (const float*)d_in[18];
    const float* mlp0_b    = (const float*)d_in[19];
    const float* mlp1_w    = (const float*)d_in[20];
    const float* mlp1_b    = (const float*)d_in[21];
    const float* fco_w     = (const float*)d_in[22];
    const float* fco_b     = (const float*)d_in[23];
    float* out = (float*)d_out;
    float* ws  = (float*)d_ws;
    float* air = ws + WS_AIR;

    precompute_kernel<<<dim3(105), dim3(256), 0, stream>>>(
        enc_air_w, enc_air_b, enc_m_w, enc_m_b, gru_wih, gru_bih,
        qln_w, qln_b, kln_w, kln_b, attn_in_w, attn_in_b, ws);

    gru_kernel<<<dim3(256), dim3(1024), 0, stream>>>(
        obs, h0, gru_whh, gru_bhh, enc_air_b, ws, air, out);

    attnmlp_kernel<<<dim3(N_/16), dim3(512), 0, stream>>>(
        obs, attn_out_w, attn_out_b, ws,
        mlp0_w, mlp0_b, mlp1_w, mlp1_b, fco_w, fco_b,
        air, out);
}

// Round 9
// 2158.133 us; speedup vs baseline: 3.2424x; 1.1014x over previous
//
#include <hip/hip_runtime.h>
#include <math.h>

#define B_   4096
#define S_   64
#define H_   128
#define N_   (B_*S_)

// ---- workspace float offsets ----
#define WS_WC    0        // [384][16]  combined obs->gi weights (padded f=16)
#define WS_BC    6144     // [384]      combined gi bias
#define WS_WAP   6528     // [128][16]  padded enc_air_w
#define WS_WQP   8576     // [128][128] wq * qln_w (folded)
#define WS_SQ    24960    // [128] row sums of wqp
#define WS_EQ    25088    // [128] wq@qln_b + bq
#define WS_KC    25216    // [128][4]  (wk*klnw)@enc_m_w
#define WS_EK1   25728    // [128] (wk*klnw)@enc_m_b
#define WS_SK    25856    // [128] rowsum(wk*klnw)
#define WS_EK2   25984    // [128] wk@kln_b + bk
#define WS_VC    26112    // [128][4]  wv@enc_m_w
#define WS_VB    26624    // [128] wv@enc_m_b + bv
#define WS_MV    26752    // [4] mean weights for keys_raw mean
#define WS_QQ    26756    // [16] 4x4 quadratic form for E[y^2]
#define WS_QLIN  26772    // [4]
#define WS_MBC   26776
#define WS_C0    26777
#define WS_AIR   27392    // [N_][128] air_feat buffer

#define AP 172     // attn row pitch
#define GP_ROW 148 // gru h row pitch (4 chunks * 36 + 4)
#define GP_CH  36  // gru chunk pitch: words 0..31 = h, 32..35 = obs slack

__device__ __forceinline__ float dot4(float4 a, float4 b){
    return fmaf(a.x,b.x, fmaf(a.y,b.y, fmaf(a.z,b.z, a.w*b.w)));
}
__device__ __forceinline__ void acc4(float& acc, float4 a, float4 b){
    acc = fmaf(a.x,b.x,acc); acc = fmaf(a.y,b.y,acc);
    acc = fmaf(a.z,b.z,acc); acc = fmaf(a.w,b.w,acc);
}
__device__ __forceinline__ int caddr(int r, int c){       // attn chunked layout
    return r*AP + (c>>5)*40 + (c&31);
}

// ---------------- precompute folded weights ----------------
__global__ void precompute_kernel(
    const float* __restrict__ enc_air_w, const float* __restrict__ enc_air_b,
    const float* __restrict__ enc_m_w,  const float* __restrict__ enc_m_b,
    const float* __restrict__ gru_wih,  const float* __restrict__ gru_bih,
    const float* __restrict__ qln_w, const float* __restrict__ qln_b,
    const float* __restrict__ kln_w, const float* __restrict__ kln_b,
    const float* __restrict__ attn_in_w, const float* __restrict__ attn_in_b,
    float* __restrict__ ws)
{
    int i = blockIdx.x*blockDim.x + threadIdx.x;
    if (i < 6144) {                       // Wc[o][f] = sum_k wih[o][k]*Wa[k][f]
        int o = i>>4, f = i&15; float a = 0.f;
        if (f < 15) for (int k=0;k<128;k++) a = fmaf(gru_wih[o*128+k], enc_air_w[k*15+f], a);
        ws[WS_WC+i] = a;
    } else if (i < 6528) {                // bc
        int o = i-6144; float a = gru_bih[o];
        for (int k=0;k<128;k++) a = fmaf(gru_wih[o*128+k], enc_air_b[k], a);
        ws[WS_BC+o] = a;
    } else if (i < 8576) {                // Wap padded
        int idx = i-6528; int j = idx>>4, f = idx&15;
        ws[WS_WAP+idx] = (f<15) ? enc_air_w[j*15+f] : 0.f;
    } else if (i < 24960) {               // wqp
        int idx = i-8576; int o = idx>>7, j = idx&127;
        ws[WS_WQP+idx] = attn_in_w[o*128+j]*qln_w[j];
    } else if (i < 25088) {               // sq
        int o = i-24960; float a=0.f;
        for (int j=0;j<128;j++) a = fmaf(attn_in_w[o*128+j], qln_w[j], a);
        ws[WS_SQ+o]=a;
    } else if (i < 25216) {               // eq
        int o = i-25088; float a = attn_in_b[o];
        for (int j=0;j<128;j++) a = fmaf(attn_in_w[o*128+j], qln_b[j], a);
        ws[WS_EQ+o]=a;
    } else if (i < 25728) {               // Kc
        int idx = i-25216; int o = idx>>2, f = idx&3; float a=0.f;
        for (int j=0;j<128;j++) a = fmaf(attn_in_w[(128+o)*128+j]*kln_w[j], enc_m_w[j*4+f], a);
        ws[WS_KC+idx]=a;
    } else if (i < 25856) {               // ek1
        int o = i-25728; float a=0.f;
        for (int j=0;j<128;j++) a = fmaf(attn_in_w[(128+o)*128+j]*kln_w[j], enc_m_b[j], a);
        ws[WS_EK1+o]=a;
    } else if (i < 25984) {               // sk
        int o = i-25856; float a=0.f;
        for (int j=0;j<128;j++) a = fmaf(attn_in_w[(128+o)*128+j], kln_w[j], a);
        ws[WS_SK+o]=a;
    } else if (i < 26112) {               // ek2
        int o = i-25984; float a = attn_in_b[128+o];
        for (int j=0;j<128;j++) a = fmaf(attn_in_w[(128+o)*128+j], kln_b[j], a);
        ws[WS_EK2+o]=a;
    } else if (i < 26624) {               // Vc
        int idx = i-26112; int o = idx>>2, f = idx&3; float a=0.f;
        for (int j=0;j<128;j++) a = fmaf(attn_in_w[(256+o)*128+j], enc_m_w[j*4+f], a);
        ws[WS_VC+idx]=a;
    } else if (i < 26752) {               // vb
        int o = i-26624; float a = attn_in_b[256+o];
        for (int j=0;j<128;j++) a = fmaf(attn_in_w[(256+o)*128+j], enc_m_b[j], a);
        ws[WS_VB+o]=a;
    } else if (i < 26756) {               // Mv
        int f = i-26752; float a=0.f;
        for (int j=0;j<128;j++) a += enc_m_w[j*4+f];
        ws[WS_MV+f]=a*(1.f/128.f);
    } else if (i < 26772) {               // QQ
        int idx = i-26756; int a4 = idx>>2, b4 = idx&3; float a=0.f;
        for (int j=0;j<128;j++) a = fmaf(enc_m_w[j*4+a4], enc_m_w[j*4+b4], a);
        ws[WS_QQ+idx]=a*(1.f/128.f);
    } else if (i < 26776) {               // qlin
        int f = i-26772; float a=0.f;
        for (int j=0;j<128;j++) a = fmaf(enc_m_b[j], enc_m_w[j*4+f], a);
        ws[WS_QLIN+f]=a*(2.f/128.f);
    } else if (i == 26776) {
        float a=0.f; for (int j=0;j<128;j++) a += enc_m_b[j];
        ws[WS_MBC]=a*(1.f/128.f);
    } else if (i == 26777) {
        float a=0.f; for (int j=0;j<128;j++) a = fmaf(enc_m_b[j], enc_m_b[j], a);
        ws[WS_C0]=a*(1.f/128.f);
    }
}

// ---------------- Kernel A: GRU, 512 threads, 128-VGPR regime ----------------
// 256 blocks x 16 rows. Thread (j=t>>2, kc=t&3) holds whh[3 gates][j][32kc..+32)
// = 96 floats + obs-folds (8). Biases via LDS. Row-at-a-time inner loop with
// #pragma unroll 1 keeps transients ~14 -> peak ~122 <= the 128 budget that
// waves_per_eu(2,2) on a 512-thr block is verified to give (R7). No spill/remat.
__global__ __launch_bounds__(512) __attribute__((amdgpu_waves_per_eu(2, 2)))
void gru_kernel(
    const float* __restrict__ obs, const float* __restrict__ h0,
    const float* __restrict__ whh, const float* __restrict__ bhh,
    const float* __restrict__ ba,  const float* __restrict__ ws,
    float* __restrict__ air, float* __restrict__ out)
{
    __shared__ float h_s[2][16*GP_ROW];
    __shared__ float air_s[16*132];
    __shared__ float wcn_s[128*20];    // Wc_n rows, pitch 20
    __shared__ float wap_s[128*20];    // Wap rows, pitch 20
    __shared__ float b5_s[5*128];      // bcrt,bczt,bcn,bhn,baj

    const int t  = threadIdx.x;
    const int j  = t>>2;        // 0..127 output column
    const int kc = t&3;         // 0..3 k-chunk (32 floats)
    const int row0 = blockIdx.x*16;

    // --- persistent weights: 96 + 8 floats ---
    const float4* whh4 = (const float4*)whh;
    const float4* ws4  = (const float4*)ws;
    float4 whr[8], whz[8], whn[8];
    #pragma unroll
    for (int i=0;i<8;i++){
        whr[i] = whh4[(      j)*32 + kc*8 + i];
        whz[i] = whh4[(128 + j)*32 + kc*8 + i];
        whn[i] = whh4[(256 + j)*32 + kc*8 + i];
    }
    const float4 wcr4 = ws4[(WS_WC>>2) + (      j)*4 + kc];   // obs cols 4kc..4kc+3
    const float4 wcz4 = ws4[(WS_WC>>2) + (128 + j)*4 + kc];
    const int hoff_j = (j>>5)*GP_CH + (j&31);

    // --- stage biases / Wc_n / Wap into LDS ---
    if (t < 128){
        b5_s[0*128+t] = ws[WS_BC+t]     + bhh[t];
        b5_s[1*128+t] = ws[WS_BC+128+t] + bhh[128+t];
        b5_s[2*128+t] = ws[WS_BC+256+t];
        b5_s[3*128+t] = bhh[256+t];
        b5_s[4*128+t] = ba[t];
    }
    {
        int f = t&15;
        #pragma unroll
        for (int it=0; it<4; it++){
            int jr = (t>>4) + 32*it;
            wcn_s[jr*20+f] = ws[WS_WC + (256+jr)*16 + f];
            wap_s[jr*20+f] = ws[WS_WAP + jr*16 + f];
        }
    }
    // --- stage h0 + obs(0) into buf0 ---
    {
        int rr = t>>5, c0 = (t&31)*4;
        float4 hv = *(const float4*)&h0[(size_t)(row0+rr)*128 + c0];
        *(float4*)&h_s[0][rr*GP_ROW + (c0>>5)*GP_CH + (c0&31)] = hv;
    }
    if (t < 256){
        int rr = t>>4, c = t&15;
        h_s[0][rr*GP_ROW + (c>>2)*GP_CH + 32 + (c&3)] =
            (c<15) ? obs[((size_t)(row0+rr)*64 + 0)*15 + c] : 0.f;
    }
    __syncthreads();

    for (int s=0;s<64;s++){
        const float* hcur = h_s[s&1];
        float*       hnxt = h_s[(s+1)&1];

        // prefetch obs(s+1) into a register (overlaps the dot phase)
        float obs_pf = 0.f;
        if (t < 256){
            int rr = t>>4, c = t&15;
            int sn = (s<63) ? s+1 : s;
            obs_pf = (c<15) ? obs[((size_t)(row0+rr)*64 + sn)*15 + c] : 0.f;
        }

        float lr=0.f, lz=0.f, ln=0.f;   // latched sums for this lane's row
        #pragma unroll 1
        for (int r=0; r<16; r++){
            const float* hb = &hcur[r*GP_ROW + kc*GP_CH];
            float pr=0.f, pz=0.f, pn=0.f;
            #pragma unroll
            for (int i=0;i<8;i++){
                float4 hv = *(const float4*)&hb[i*4];
                acc4(pr,hv,whr[i]); acc4(pz,hv,whz[i]); acc4(pn,hv,whn[i]);
            }
            {
                float4 o4 = *(const float4*)&hb[32];   // obs slack for this chunk
                acc4(pr, o4, wcr4);
                acc4(pz, o4, wcz4);
            }
            // reduce over kc quartet (lanes differ in bits 0..1)
            pr += __shfl_xor(pr,1); pr += __shfl_xor(pr,2);
            pz += __shfl_xor(pz,1); pz += __shfl_xor(pz,2);
            pn += __shfl_xor(pn,1); pn += __shfl_xor(pn,2);
            bool own = ((r&3)==kc);
            lr = own ? pr : lr;  lz = own ? pz : lz;  ln = own ? pn : ln;

            if ((r&3)==3){
                // finalize row (r-3)+kc : all 64 lanes active, distinct (row,j)
                const int rr = (r-3) + kc;
                const float* rb = &hcur[rr*GP_ROW];
                float gin = b5_s[2*128+j];
                float ae  = b5_s[4*128+j];
                #pragma unroll
                for (int c=0;c<4;c++){
                    float4 oc = *(const float4*)&rb[c*GP_CH+32];
                    acc4(gin, oc, *(const float4*)&wcn_s[j*20+c*4]);
                    acc4(ae,  oc, *(const float4*)&wap_s[j*20+c*4]);
                }
                float rg = 1.f/(1.f+__expf(-(lr + b5_s[0*128+j])));
                float zg = 1.f/(1.f+__expf(-(lz + b5_s[1*128+j])));
                float nx = fmaf(rg, ln + b5_s[3*128+j], gin);
                float e2 = __expf(2.f*nx);
                float ng = 1.f - 2.f/(e2+1.f);          // tanh(nx)
                float hold = rb[hoff_j];
                float hn = fmaf(zg, hold-ng, ng);       // (1-z)n + z*h
                hnxt[rr*GP_ROW + hoff_j] = hn;          // other buffer: safe pre-barrier
                air_s[rr*132 + j] = hn + ae;
                if (s==63) out[(size_t)N_ + (size_t)(row0+rr)*128 + j] = hn;
            }
        }
        __syncthreads();   // bar_1: hcur reads done; hnxt h-region + air_s written

        // ---- coalesced air write + commit prefetched obs(s+1) into hnxt slack ----
        {
            int rr = t>>5, c0 = (t&31)*4;
            float4 av = *(const float4*)&air_s[rr*132 + c0];
            *(float4*)&air[((size_t)(row0+rr)*64 + s)*128 + c0] = av;
        }
        if (t < 256){
            int rr = t>>4, c = t&15;
            hnxt[rr*GP_ROW + (c>>2)*GP_CH + 32 + (c&3)] = obs_pf;
        }
        __syncthreads();   // bar_2: hnxt complete
    }
}

// ---------------- Kernel B: fused attention + MLP head ----------------
// waves_per_eu(2,2): 128-VGPR budget keeps the 64 persistent weight floats
// resident (R8's (2,4) collapsed to 64 regs -> remat, VALUBusy 47%).
__global__ __launch_bounds__(512) __attribute__((amdgpu_waves_per_eu(2, 2)))
void attnmlp_kernel(
    const float* __restrict__ obs, const float* __restrict__ wo,
    const float* __restrict__ bo,  const float* __restrict__ ws,
    const float* __restrict__ w0, const float* __restrict__ b0,
    const float* __restrict__ w1, const float* __restrict__ b1,
    const float* __restrict__ fcw, const float* __restrict__ fcb,
    const float* __restrict__ air, float* __restrict__ out)
{
    __shared__ float X_s[16*AP];
    __shared__ float ctx_s[16*AP];     // ctx, later h1
    __shared__ float comb_s[16*AP];
    __shared__ float obs_m[16][8];
    __shared__ float part[16][2][8];
    __shared__ float attn_s[16][4][2];
    __shared__ float mu_s[16], rs_s[16];
    __shared__ float kmu_s[16][2], krs_s[16][2];
    __shared__ int   kmask_s[16][2];
    __shared__ int   bothm_s[16];

    const int t = threadIdx.x;
    const int j = t>>2, kc = t&3;
    const int w = t>>6;
    const int n0 = blockIdx.x*16;
    const int jaddr_off = (j>>5)*40 + (j&31);

    // phase-1 weights
    const float4* wqp4 = (const float4*)(ws + WS_WQP);
    const float4* wo4g = (const float4*)wo;
    float4 wa4[8], wb4[8];
    #pragma unroll
    for (int i=0;i<8;i++){ wa4[i] = wqp4[j*32 + kc*8 + i]; wb4[i] = wo4g[j*32 + kc*8 + i]; }
    const float sqj = ws[WS_SQ+j], eqj = ws[WS_EQ+j];
    const float4 kcj = ((const float4*)(ws+WS_KC))[j];
    const float ek1j = ws[WS_EK1+j], skj = ws[WS_SK+j], ek2j = ws[WS_EK2+j];
    const float4 vcj = ((const float4*)(ws+WS_VC))[j];
    const float vbj = ws[WS_VB+j];
    const float boj = bo[j];
    const float b0j = b0[j], b1j = b1[j], fcj = fcw[j];

    // stage X tile + LN stats + missile staging/stats
    {
        int rr = t>>5, c0 = (t&31)*4;
        float4 xv = *(const float4*)&air[(size_t)(n0+rr)*128 + c0];
        *(float4*)&X_s[caddr(rr,c0)] = xv;
        float sm = xv.x+xv.y+xv.z+xv.w;
        float s2 = fmaf(xv.x,xv.x, fmaf(xv.y,xv.y, fmaf(xv.z,xv.z, xv.w*xv.w)));
        #pragma unroll
        for (int m=1;m<32;m<<=1){ sm += __shfl_xor(sm,m); s2 += __shfl_xor(s2,m); }
        if ((t&31)==0){
            float mu = sm*(1.f/128.f);
            float var = s2*(1.f/128.f) - mu*mu;
            mu_s[rr]=mu; rs_s[rr]=rsqrtf(var+1e-5f);
        }
    }
    if (t>=128 && t<256){
        int idx = t-128; int rr = idx>>3, f = idx&7;
        obs_m[rr][f] = obs[(size_t)(n0+rr)*15 + f];
    }
    if (t<32){
        int rr = t&15, mi = t>>4;
        const float* mp = &obs[(size_t)(n0+rr)*15 + mi*4];
        float m0=mp[0], m1=mp[1], m2=mp[2], m3=mp[3];
        const float tol1 = 1e-8f + 1e-5f, tol0 = 1e-8f;
        kmask_s[rr][mi] = (fabsf(m0-1.f)<=tol1)&&(fabsf(m1)<=tol0)&&
                          (fabsf(m2-1.f)<=tol1)&&(fabsf(m3)<=tol0);
        float mv[4]={m0,m1,m2,m3};
        float mu = ws[WS_MBC];
        #pragma unroll
        for (int f=0;f<4;f++) mu = fmaf(ws[WS_MV+f], mv[f], mu);
        float e2 = ws[WS_C0];
        #pragma unroll
        for (int a4=0;a4<4;a4++){
            e2 = fmaf(ws[WS_QLIN+a4], mv[a4], e2);
            #pragma unroll
            for (int b4=0;b4<4;b4++) e2 = fmaf(ws[WS_QQ+a4*4+b4]*mv[a4], mv[b4], e2);
        }
        float var = e2 - mu*mu;
        kmu_s[rr][mi]=mu; krs_s[rr][mi]=rsqrtf(var+1e-5f);
    }
    __syncthreads();

    // q matvec (folded LN): kc-butterfly, owner keeps rows 4kc..4kc+3
    float qown[4];
    #pragma unroll
    for (int r=0;r<16;r++){
        float acc = 0.f;
        const float* xb = &X_s[r*AP + kc*40];
        #pragma unroll
        for (int i=0;i<8;i++) acc4(acc, *(const float4*)&xb[i*4], wa4[i]);
        acc += __shfl_xor(acc,1); acc += __shfl_xor(acc,2);
        if (kc == (r>>2)) qown[r&3] = acc;
    }
    // scores
    #pragma unroll
    for (int oi=0;oi<4;oi++){
        int r = kc*4 + oi;
        float qv = fmaf(rs_s[r], qown[oi] - mu_s[r]*sqj, eqj);
        float4 m0v = *(const float4*)&obs_m[r][0];
        float4 m1v = *(const float4*)&obs_m[r][4];
        float k0 = fmaf(krs_s[r][0], dot4(kcj,m0v)+ek1j - kmu_s[r][0]*skj, ek2j);
        float k1 = fmaf(krs_s[r][1], dot4(kcj,m1v)+ek1j - kmu_s[r][1]*skj, ek2j);
        float p0 = qv*k0, p1 = qv*k1;
        #pragma unroll
        for (int m=4;m<64;m<<=1){ p0 += __shfl_xor(p0,m); p1 += __shfl_xor(p1,m); }
        if ((t&63)==kc){ part[r][0][w]=p0; part[r][1][w]=p1; }
    }
    __syncthreads();
    if (t<64){
        int rr = t&15, hd = t>>4;
        float s0 = part[rr][0][2*hd] + part[rr][0][2*hd+1];
        float s1 = part[rr][1][2*hd] + part[rr][1][2*hd+1];
        const float scale = 0.17677669529663687f;  // 1/sqrt(32)
        s0 *= scale; s1 *= scale;
        int m0 = kmask_s[rr][0], m1 = kmask_s[rr][1];
        float a0, a1;
        if (m0 && m1) { a0=0.f; a1=0.f; if (hd==0) bothm_s[rr]=1; }
        else {
            if (hd==0) bothm_s[rr]=0;
            if (m0)      { a0=0.f; a1=1.f; }
            else if (m1) { a0=1.f; a1=0.f; }
            else {
                float mx = fmaxf(s0,s1);
                float e0 = __expf(s0-mx), e1 = __expf(s1-mx);
                float inv = 1.f/(e0+e1);
                a0 = e0*inv; a1 = e1*inv;
            }
        }
        attn_s[rr][hd][0]=a0; attn_s[rr][hd][1]=a1;
    }
    __syncthreads();
    // ctx (v on the fly)
    {
        int hd = j>>5;
        #pragma unroll
        for (int oi=0;oi<4;oi++){
            int r = kc*4 + oi;
            float4 m0v = *(const float4*)&obs_m[r][0];
            float4 m1v = *(const float4*)&obs_m[r][4];
            float v0 = dot4(vcj,m0v)+vbj, v1 = dot4(vcj,m1v)+vbj;
            ctx_s[r*AP + jaddr_off] = attn_s[r][hd][0]*v0 + attn_s[r][hd][1]*v1;
        }
    }
    __syncthreads();
    // attn_out matvec + nan guard + residual -> comb_s
    {
        float aown[4];
        #pragma unroll
        for (int r=0;r<16;r++){
            float acc = 0.f;
            const float* zb = &ctx_s[r*AP + kc*40];
            #pragma unroll
            for (int i=0;i<8;i++) acc4(acc, *(const float4*)&zb[i*4], wb4[i]);
            acc += __shfl_xor(acc,1); acc += __shfl_xor(acc,2);
            if (kc == (r>>2)) aown[r&3] = acc;
        }
        #pragma unroll
        for (int oi=0;oi<4;oi++){
            int r = kc*4 + oi;
            float ao = bothm_s[r] ? 0.f : (aown[oi] + boj);
            comb_s[r*AP + jaddr_off] = X_s[r*AP + jaddr_off] + ao;
        }
    }
    // ---- phase 2: reload weight regs with mlp weights ----
    {
        const float4* w04g = (const float4*)w0;
        const float4* w14g = (const float4*)w1;
        #pragma unroll
        for (int i=0;i<8;i++){ wa4[i] = w04g[j*32 + kc*8 + i]; wb4[i] = w14g[j*32 + kc*8 + i]; }
    }
    __syncthreads();   // comb_s complete; ctx_s reads done (reused as H below)
    // mlp0 -> ctx_s (reused as h1)
    {
        float hown[4];
        #pragma unroll
        for (int r=0;r<16;r++){
            float acc = 0.f;
            const float* cb = &comb_s[r*AP + kc*40];
            #pragma unroll
            for (int i=0;i<8;i++) acc4(acc, *(const float4*)&cb[i*4], wa4[i]);
            acc += __shfl_xor(acc,1); acc += __shfl_xor(acc,2);
            if (kc == (r>>2)){
                float v = acc + b0j;
                hown[r&3] = (v > 0.f) ? v : 0.01f*v;
            }
        }
        #pragma unroll
        for (int oi=0;oi<4;oi++) ctx_s[(kc*4+oi)*AP + jaddr_off] = hown[oi];
    }
    __syncthreads();
    // mlp1 + leaky + fco partial
    {
        float pown[4];
        #pragma unroll
        for (int r=0;r<16;r++){
            float acc = 0.f;
            const float* hb = &ctx_s[r*AP + kc*40];
            #pragma unroll
            for (int i=0;i<8;i++) acc4(acc, *(const float4*)&hb[i*4], wb4[i]);
            acc += __shfl_xor(acc,1); acc += __shfl_xor(acc,2);
            if (kc == (r>>2)){
                float v = acc + b1j;
                v = (v > 0.f) ? v : 0.01f*v;
                pown[r&3] = v * fcj;
            }
        }
        #pragma unroll
        for (int oi=0;oi<4;oi++){
            float p = pown[oi];
            #pragma unroll
            for (int m=4;m<64;m<<=1) p += __shfl_xor(p,m);
            if ((t&63)==kc) part[kc*4+oi][0][w] = p;
        }
    }
    __syncthreads();
    if (t<16){
        float a = 0.f;
        #pragma unroll
        for (int k=0;k<8;k++) a += part[t][0][k];
        out[n0 + t] = a + fcb[0];
    }
}

extern "C" void kernel_launch(void* const* d_in, const int* in_sizes, int n_in,
                              void* d_out, int out_size, void* d_ws, size_t ws_size,
                              hipStream_t stream) {
    const float* obs       = (const float*)d_in[0];
    const float* h0        = (const float*)d_in[1];
    const float* enc_air_w = (const float*)d_in[2];
    const float* enc_air_b = (const float*)d_in[3];
    const float* enc_m_w   = (const float*)d_in[4];
    const float* enc_m_b   = (const float*)d_in[5];
    const float* gru_wih   = (const float*)d_in[6];
    const float* gru_whh   = (const float*)d_in[7];
    const float* gru_bih   = (const float*)d_in[8];
    const float* gru_bhh   = (const float*)d_in[9];
    const float* qln_w     = (const float*)d_in[10];
    const float* qln_b     = (const float*)d_in[11];
    const float* kln_w     = (const float*)d_in[12];
    const float* kln_b     = (const float*)d_in[13];
    const float* attn_in_w = (const float*)d_in[14];
    const float* attn_in_b = (const float*)d_in[15];
    const float* attn_out_w= (const float*)d_in[16];
    const float* attn_out_b= (const float*)d_in[17];
    const float* mlp0_w    = (const float*)d_in[18];
    const float* mlp0_b    = (const float*)d_in[19];
    const float* mlp1_w    = (const float*)d_in[20];
    const float* mlp1_b    = (const float*)d_in[21];
    const float* fco_w     = (const float*)d_in[22];
    const float* fco_b     = (const float*)d_in[23];
    float* out = (float*)d_out;
    float* ws  = (float*)d_ws;
    float* air = ws + WS_AIR;

    precompute_kernel<<<dim3(105), dim3(256), 0, stream>>>(
        enc_air_w, enc_air_b, enc_m_w, enc_m_b, gru_wih, gru_bih,
        qln_w, qln_b, kln_w, kln_b, attn_in_w, attn_in_b, ws);

    gru_kernel<<<dim3(256), dim3(512), 0, stream>>>(
        obs, h0, gru_whh, gru_bhh, enc_air_b, ws, air, out);

    attnmlp_kernel<<<dim3(N_/16), dim3(512), 0, stream>>>(
        obs, attn_out_w, attn_out_b, ws,
        mlp0_w, mlp0_b, mlp1_w, mlp1_b, fco_w, fco_b,
        air, out);
}

// Round 10
// 842.437 us; speedup vs baseline: 8.3063x; 2.5618x over previous
//
#include <hip/hip_runtime.h>
#include <math.h>

#define B_   4096
#define S_   64
#define H_   128
#define N_   (B_*S_)

// ---- workspace float offsets ----
#define WS_WC    0        // [384][16]  combined obs->gi weights (padded f=16)
#define WS_BC    6144     // [384]      combined gi bias
#define WS_WAP   6528     // [128][16]  padded enc_air_w
#define WS_WQP   8576     // [128][128] wq * qln_w (folded; fp32 copy, unused by attnmlp now)
#define WS_SQ    24960    // [128] row sums of wqp
#define WS_EQ    25088    // [128] wq@qln_b + bq
#define WS_KC    25216    // [128][4]  (wk*klnw)@enc_m_w
#define WS_EK1   25728    // [128] (wk*klnw)@enc_m_b
#define WS_SK    25856    // [128] rowsum(wk*klnw)
#define WS_EK2   25984    // [128] wk@kln_b + bk
#define WS_VC    26112    // [128][4]  wv@enc_m_w
#define WS_VB    26624    // [128] wv@enc_m_b + bv
#define WS_MV    26752    // [4] mean weights for keys_raw mean
#define WS_QQ    26756    // [16] 4x4 quadratic form for E[y^2]
#define WS_QLIN  26772    // [4]
#define WS_MBC   26776
#define WS_C0    26777
#define WS_PB    27392    // packed bf16 B-fragments: 4 matrices x 16384 ushort (32768 floats)
#define WS_AIR   60160    // [N_][128] air_feat buffer

#define GP_ROW 148 // gru h row pitch (4 chunks * 36 + 4)
#define GP_CH  36  // gru chunk pitch: words 0..31 = h, 32..35 = obs slack

typedef __attribute__((ext_vector_type(8))) short bf16x8;
typedef __attribute__((ext_vector_type(4))) float f32x4;

__device__ __forceinline__ float dot4(float4 a, float4 b){
    return fmaf(a.x,b.x, fmaf(a.y,b.y, fmaf(a.z,b.z, a.w*b.w)));
}
__device__ __forceinline__ void acc4(float& acc, float4 a, float4 b){
    acc = fmaf(a.x,b.x,acc); acc = fmaf(a.y,b.y,acc);
    acc = fmaf(a.z,b.z,acc); acc = fmaf(a.w,b.w,acc);
}
__device__ __forceinline__ unsigned short f2bf(float f){   // RNE fp32->bf16
    union { float f; unsigned u; } v; v.f = f;
    unsigned r = v.u + 0x7FFF + ((v.u >> 16) & 1);
    return (unsigned short)(r >> 16);
}
__device__ __forceinline__ float bf2f(unsigned short u){
    union { unsigned u; float f; } v; v.u = ((unsigned)u) << 16;
    return v.f;
}

// ---------------- precompute folded weights + packed bf16 B-frags ----------------
__global__ void precompute_kernel(
    const float* __restrict__ enc_air_w, const float* __restrict__ enc_air_b,
    const float* __restrict__ enc_m_w,  const float* __restrict__ enc_m_b,
    const float* __restrict__ gru_wih,  const float* __restrict__ gru_bih,
    const float* __restrict__ qln_w, const float* __restrict__ qln_b,
    const float* __restrict__ kln_w, const float* __restrict__ kln_b,
    const float* __restrict__ attn_in_w, const float* __restrict__ attn_in_b,
    const float* __restrict__ attn_out_w,
    const float* __restrict__ mlp0_w, const float* __restrict__ mlp1_w,
    float* __restrict__ ws)
{
    int i = blockIdx.x*blockDim.x + threadIdx.x;
    if (i < 6144) {                       // Wc[o][f] = sum_k wih[o][k]*Wa[k][f]
        int o = i>>4, f = i&15; float a = 0.f;
        if (f < 15) for (int k=0;k<128;k++) a = fmaf(gru_wih[o*128+k], enc_air_w[k*15+f], a);
        ws[WS_WC+i] = a;
    } else if (i < 6528) {                // bc
        int o = i-6144; float a = gru_bih[o];
        for (int k=0;k<128;k++) a = fmaf(gru_wih[o*128+k], enc_air_b[k], a);
        ws[WS_BC+o] = a;
    } else if (i < 8576) {                // Wap padded
        int idx = i-6528; int j = idx>>4, f = idx&15;
        ws[WS_WAP+idx] = (f<15) ? enc_air_w[j*15+f] : 0.f;
    } else if (i < 24960) {               // wqp (fp32 copy, kept)
        int idx = i-8576; int o = idx>>7, j = idx&127;
        ws[WS_WQP+idx] = attn_in_w[o*128+j]*qln_w[j];
    } else if (i < 25088) {               // sq
        int o = i-24960; float a=0.f;
        for (int j=0;j<128;j++) a = fmaf(attn_in_w[o*128+j], qln_w[j], a);
        ws[WS_SQ+o]=a;
    } else if (i < 25216) {               // eq
        int o = i-25088; float a = attn_in_b[o];
        for (int j=0;j<128;j++) a = fmaf(attn_in_w[o*128+j], qln_b[j], a);
        ws[WS_EQ+o]=a;
    } else if (i < 25728) {               // Kc
        int idx = i-25216; int o = idx>>2, f = idx&3; float a=0.f;
        for (int j=0;j<128;j++) a = fmaf(attn_in_w[(128+o)*128+j]*kln_w[j], enc_m_w[j*4+f], a);
        ws[WS_KC+idx]=a;
    } else if (i < 25856) {               // ek1
        int o = i-25728; float a=0.f;
        for (int j=0;j<128;j++) a = fmaf(attn_in_w[(128+o)*128+j]*kln_w[j], enc_m_b[j], a);
        ws[WS_EK1+o]=a;
    } else if (i < 25984) {               // sk
        int o = i-25856; float a=0.f;
        for (int j=0;j<128;j++) a = fmaf(attn_in_w[(128+o)*128+j], kln_w[j], a);
        ws[WS_SK+o]=a;
    } else if (i < 26112) {               // ek2
        int o = i-25984; float a = attn_in_b[128+o];
        for (int j=0;j<128;j++) a = fmaf(attn_in_w[(128+o)*128+j], kln_b[j], a);
        ws[WS_EK2+o]=a;
    } else if (i < 26624) {               // Vc
        int idx = i-26112; int o = idx>>2, f = idx&3; float a=0.f;
        for (int j=0;j<128;j++) a = fmaf(attn_in_w[(256+o)*128+j], enc_m_w[j*4+f], a);
        ws[WS_VC+idx]=a;
    } else if (i < 26752) {               // vb
        int o = i-26624; float a = attn_in_b[256+o];
        for (int j=0;j<128;j++) a = fmaf(attn_in_w[(256+o)*128+j], enc_m_b[j], a);
        ws[WS_VB+o]=a;
    } else if (i < 26756) {               // Mv
        int f = i-26752; float a=0.f;
        for (int j=0;j<128;j++) a += enc_m_w[j*4+f];
        ws[WS_MV+f]=a*(1.f/128.f);
    } else if (i < 26772) {               // QQ
        int idx = i-26756; int a4 = idx>>2, b4 = idx&3; float a=0.f;
        for (int j=0;j<128;j++) a = fmaf(enc_m_w[j*4+a4], enc_m_w[j*4+b4], a);
        ws[WS_QQ+idx]=a*(1.f/128.f);
    } else if (i < 26776) {               // qlin
        int f = i-26772; float a=0.f;
        for (int j=0;j<128;j++) a = fmaf(enc_m_b[j], enc_m_w[j*4+f], a);
        ws[WS_QLIN+f]=a*(2.f/128.f);
    } else if (i == 26776) {
        float a=0.f; for (int j=0;j<128;j++) a += enc_m_b[j];
        ws[WS_MBC]=a*(1.f/128.f);
    } else if (i == 26777) {
        float a=0.f; for (int j=0;j<128;j++) a = fmaf(enc_m_b[j], enc_m_b[j], a);
        ws[WS_C0]=a*(1.f/128.f);
    } else if (i >= 32768 && i < 98304) {
        // packed bf16 B-fragments for mfma_f32_16x16x32_bf16 (m97 gemm_bt convention):
        // frag elem: B[n = 16w + (l&15)][k = 32p + (l>>4)*8 + i8]
        int idx = i - 32768;              // 0..65535
        int i8 = idx & 7, l = (idx>>3)&63, p = (idx>>9)&3, wv = (idx>>11)&7, mm = idx>>14;
        int n = 16*wv + (l&15);
        int k = 32*p + ((l>>4)<<3) + i8;
        float v;
        if      (mm==0) v = attn_in_w[n*128+k]*qln_w[k];   // wqp (folded q-LN)
        else if (mm==1) v = attn_out_w[n*128+k];
        else if (mm==2) v = mlp0_w[n*128+k];
        else            v = mlp1_w[n*128+k];
        ((unsigned short*)(ws+WS_PB))[idx] = f2bf(v);
    }
}

// ---------------- Kernel A: GRU (R9 verified, unchanged) ----------------
__global__ __launch_bounds__(512) __attribute__((amdgpu_waves_per_eu(2, 2)))
void gru_kernel(
    const float* __restrict__ obs, const float* __restrict__ h0,
    const float* __restrict__ whh, const float* __restrict__ bhh,
    const float* __restrict__ ba,  const float* __restrict__ ws,
    float* __restrict__ air, float* __restrict__ out)
{
    __shared__ float h_s[2][16*GP_ROW];
    __shared__ float air_s[16*132];
    __shared__ float wcn_s[128*20];    // Wc_n rows, pitch 20
    __shared__ float wap_s[128*20];    // Wap rows, pitch 20
    __shared__ float b5_s[5*128];      // bcrt,bczt,bcn,bhn,baj

    const int t  = threadIdx.x;
    const int j  = t>>2;        // 0..127 output column
    const int kc = t&3;         // 0..3 k-chunk (32 floats)
    const int row0 = blockIdx.x*16;

    const float4* whh4 = (const float4*)whh;
    const float4* ws4  = (const float4*)ws;
    float4 whr[8], whz[8], whn[8];
    #pragma unroll
    for (int i=0;i<8;i++){
        whr[i] = whh4[(      j)*32 + kc*8 + i];
        whz[i] = whh4[(128 + j)*32 + kc*8 + i];
        whn[i] = whh4[(256 + j)*32 + kc*8 + i];
    }
    const float4 wcr4 = ws4[(WS_WC>>2) + (      j)*4 + kc];
    const float4 wcz4 = ws4[(WS_WC>>2) + (128 + j)*4 + kc];
    const int hoff_j = (j>>5)*GP_CH + (j&31);

    if (t < 128){
        b5_s[0*128+t] = ws[WS_BC+t]     + bhh[t];
        b5_s[1*128+t] = ws[WS_BC+128+t] + bhh[128+t];
        b5_s[2*128+t] = ws[WS_BC+256+t];
        b5_s[3*128+t] = bhh[256+t];
        b5_s[4*128+t] = ba[t];
    }
    {
        int f = t&15;
        #pragma unroll
        for (int it=0; it<4; it++){
            int jr = (t>>4) + 32*it;
            wcn_s[jr*20+f] = ws[WS_WC + (256+jr)*16 + f];
            wap_s[jr*20+f] = ws[WS_WAP + jr*16 + f];
        }
    }
    {
        int rr = t>>5, c0 = (t&31)*4;
        float4 hv = *(const float4*)&h0[(size_t)(row0+rr)*128 + c0];
        *(float4*)&h_s[0][rr*GP_ROW + (c0>>5)*GP_CH + (c0&31)] = hv;
    }
    if (t < 256){
        int rr = t>>4, c = t&15;
        h_s[0][rr*GP_ROW + (c>>2)*GP_CH + 32 + (c&3)] =
            (c<15) ? obs[((size_t)(row0+rr)*64 + 0)*15 + c] : 0.f;
    }
    __syncthreads();

    for (int s=0;s<64;s++){
        const float* hcur = h_s[s&1];
        float*       hnxt = h_s[(s+1)&1];

        float obs_pf = 0.f;
        if (t < 256){
            int rr = t>>4, c = t&15;
            int sn = (s<63) ? s+1 : s;
            obs_pf = (c<15) ? obs[((size_t)(row0+rr)*64 + sn)*15 + c] : 0.f;
        }

        float lr=0.f, lz=0.f, ln=0.f;
        #pragma unroll 1
        for (int r=0; r<16; r++){
            const float* hb = &hcur[r*GP_ROW + kc*GP_CH];
            float pr=0.f, pz=0.f, pn=0.f;
            #pragma unroll
            for (int i=0;i<8;i++){
                float4 hv = *(const float4*)&hb[i*4];
                acc4(pr,hv,whr[i]); acc4(pz,hv,whz[i]); acc4(pn,hv,whn[i]);
            }
            {
                float4 o4 = *(const float4*)&hb[32];
                acc4(pr, o4, wcr4);
                acc4(pz, o4, wcz4);
            }
            pr += __shfl_xor(pr,1); pr += __shfl_xor(pr,2);
            pz += __shfl_xor(pz,1); pz += __shfl_xor(pz,2);
            pn += __shfl_xor(pn,1); pn += __shfl_xor(pn,2);
            bool own = ((r&3)==kc);
            lr = own ? pr : lr;  lz = own ? pz : lz;  ln = own ? pn : ln;

            if ((r&3)==3){
                const int rr = (r-3) + kc;
                const float* rb = &hcur[rr*GP_ROW];
                float gin = b5_s[2*128+j];
                float ae  = b5_s[4*128+j];
                #pragma unroll
                for (int c=0;c<4;c++){
                    float4 oc = *(const float4*)&rb[c*GP_CH+32];
                    acc4(gin, oc, *(const float4*)&wcn_s[j*20+c*4]);
                    acc4(ae,  oc, *(const float4*)&wap_s[j*20+c*4]);
                }
                float rg = 1.f/(1.f+__expf(-(lr + b5_s[0*128+j])));
                float zg = 1.f/(1.f+__expf(-(lz + b5_s[1*128+j])));
                float nx = fmaf(rg, ln + b5_s[3*128+j], gin);
                float e2 = __expf(2.f*nx);
                float ng = 1.f - 2.f/(e2+1.f);
                float hold = rb[hoff_j];
                float hn = fmaf(zg, hold-ng, ng);
                hnxt[rr*GP_ROW + hoff_j] = hn;
                air_s[rr*132 + j] = hn + ae;
                if (s==63) out[(size_t)N_ + (size_t)(row0+rr)*128 + j] = hn;
            }
        }
        __syncthreads();

        {
            int rr = t>>5, c0 = (t&31)*4;
            float4 av = *(const float4*)&air_s[rr*132 + c0];
            *(float4*)&air[((size_t)(row0+rr)*64 + s)*128 + c0] = av;
        }
        if (t < 256){
            int rr = t>>4, c = t&15;
            hnxt[rr*GP_ROW + (c>>2)*GP_CH + 32 + (c&3)] = obs_pf;
        }
        __syncthreads();
    }
}

// ---------------- Kernel B: attention + MLP via bf16 MFMA ----------------
// 16 tokens/block, 8 waves; wave w owns output cols [16w,16w+16).
// Each 128x128 matvec = 4 x mfma_f32_16x16x32_bf16.
// A-frag: A[m=lane&15][k=quad*8+i] (one ds_read_b128 from bf16 LDS, pitch 136).
// B-frag: packed by precompute (W[n=16w+col][k=32p+quad*8+i]).
// D: row(token)=quad*4+reg, col(j)=lane&15.
__global__ __launch_bounds__(512) void attnmlp_kernel(
    const float* __restrict__ obs, const float* __restrict__ bo,
    const float* __restrict__ ws,
    const float* __restrict__ b0, const float* __restrict__ b1,
    const float* __restrict__ fcw, const float* __restrict__ fcb,
    const float* __restrict__ air, float* __restrict__ out)
{
    __shared__ __align__(16) unsigned short X_bf[16*136];
    __shared__ __align__(16) unsigned short Y_bf[16*136];
    __shared__ __align__(16) unsigned short Z_bf[16*136];
    __shared__ float obs_m[16][12];
    __shared__ float part[16][2][8];
    __shared__ float attn_s[16][4][2];
    __shared__ float mu_s[16], rs_s[16];
    __shared__ float kmu_s[16][2], krs_s[16][2];
    __shared__ int   kmask_s[16][2];
    __shared__ int   bothm_s[16];

    const int t = threadIdx.x;
    const int w = t>>6;          // wave 0..7
    const int l = t&63;          // lane
    const int quad = l>>4;       // 0..3
    const int col  = l&15;       // 0..15
    const int jj   = 16*w + col; // this lane's output column j
    const int n0 = blockIdx.x*16;

    const unsigned short* pbu = (const unsigned short*)(ws + WS_PB);

    // ---- stage X (fp32->bf16) + LN stats + missile staging/stats ----
    {
        int rr = t>>5, c0 = (t&31)*4;
        float4 xv = *(const float4*)&air[(size_t)(n0+rr)*128 + c0];
        unsigned long long pk = (unsigned long long)f2bf(xv.x)
              | ((unsigned long long)f2bf(xv.y)<<16)
              | ((unsigned long long)f2bf(xv.z)<<32)
              | ((unsigned long long)f2bf(xv.w)<<48);
        *(unsigned long long*)&X_bf[rr*136 + c0] = pk;
        float sm = xv.x+xv.y+xv.z+xv.w;
        float s2 = fmaf(xv.x,xv.x, fmaf(xv.y,xv.y, fmaf(xv.z,xv.z, xv.w*xv.w)));
        #pragma unroll
        for (int m=1;m<32;m<<=1){ sm += __shfl_xor(sm,m); s2 += __shfl_xor(s2,m); }
        if ((t&31)==0){
            float mu = sm*(1.f/128.f);
            float var = s2*(1.f/128.f) - mu*mu;
            mu_s[rr]=mu; rs_s[rr]=rsqrtf(var+1e-5f);
        }
    }
    if (t>=128 && t<256){
        int idx = t-128; int rr = idx>>3, f = idx&7;
        obs_m[rr][f] = obs[(size_t)(n0+rr)*15 + f];
    }
    if (t<32){
        int rr = t&15, mi = t>>4;
        const float* mp = &obs[(size_t)(n0+rr)*15 + mi*4];
        float m0=mp[0], m1=mp[1], m2=mp[2], m3=mp[3];
        const float tol1 = 1e-8f + 1e-5f, tol0 = 1e-8f;
        kmask_s[rr][mi] = (fabsf(m0-1.f)<=tol1)&&(fabsf(m1)<=tol0)&&
                          (fabsf(m2-1.f)<=tol1)&&(fabsf(m3)<=tol0);
        float mv[4]={m0,m1,m2,m3};
        float mu = ws[WS_MBC];
        #pragma unroll
        for (int f=0;f<4;f++) mu = fmaf(ws[WS_MV+f], mv[f], mu);
        float e2 = ws[WS_C0];
        #pragma unroll
        for (int a4=0;a4<4;a4++){
            e2 = fmaf(ws[WS_QLIN+a4], mv[a4], e2);
            #pragma unroll
            for (int b4=0;b4<4;b4++) e2 = fmaf(ws[WS_QQ+a4*4+b4]*mv[a4], mv[b4], e2);
        }
        float var = e2 - mu*mu;
        kmu_s[rr][mi]=mu; krs_s[rr][mi]=rsqrtf(var+1e-5f);
    }
    __syncthreads();

    // ---- q matvec (MFMA, wqp = matrix 0) + scores ----
    {
        f32x4 acc = {0.f,0.f,0.f,0.f};
        #pragma unroll
        for (int p=0;p<4;p++){
            bf16x8 a = *(const bf16x8*)&X_bf[col*136 + p*32 + quad*8];
            bf16x8 b = *(const bf16x8*)&pbu[((0*32 + w*4 + p)*64 + l)*8];
            acc = __builtin_amdgcn_mfma_f32_16x16x32_bf16(a, b, acc, 0, 0, 0);
        }
        // affine: q = rs*(qraw - mu*sq[j]) + eq[j], per (token=quad*4+reg, j=jj)
        const float sqj = ws[WS_SQ+jj], eqj = ws[WS_EQ+jj];
        const float4 kcj = ((const float4*)(ws+WS_KC))[jj];
        const float ek1j = ws[WS_EK1+jj], skj = ws[WS_SK+jj], ek2j = ws[WS_EK2+jj];
        float p0v[4], p1v[4];
        #pragma unroll
        for (int reg=0;reg<4;reg++){
            int tok = quad*4 + reg;
            float qv = fmaf(rs_s[tok], acc[reg] - mu_s[tok]*sqj, eqj);
            float4 m0v = *(const float4*)&obs_m[tok][0];
            float4 m1v = *(const float4*)&obs_m[tok][4];
            float k0 = fmaf(krs_s[tok][0], dot4(kcj,m0v)+ek1j - kmu_s[tok][0]*skj, ek2j);
            float k1 = fmaf(krs_s[tok][1], dot4(kcj,m1v)+ek1j - kmu_s[tok][1]*skj, ek2j);
            p0v[reg] = qv*k0; p1v[reg] = qv*k1;
        }
        #pragma unroll
        for (int m=1;m<16;m<<=1){
            #pragma unroll
            for (int reg=0;reg<4;reg++){
                p0v[reg] += __shfl_xor(p0v[reg], m);
                p1v[reg] += __shfl_xor(p1v[reg], m);
            }
        }
        if (col==0){
            #pragma unroll
            for (int reg=0;reg<4;reg++){
                part[quad*4+reg][0][w] = p0v[reg];
                part[quad*4+reg][1][w] = p1v[reg];
            }
        }
    }
    __syncthreads();

    // ---- softmax over 2 keys per head (head hd sums waves 2hd,2hd+1) ----
    if (t<64){
        int rr = t&15, hd = t>>4;
        float s0 = part[rr][0][2*hd] + part[rr][0][2*hd+1];
        float s1 = part[rr][1][2*hd] + part[rr][1][2*hd+1];
        const float scale = 0.17677669529663687f;  // 1/sqrt(32)
        s0 *= scale; s1 *= scale;
        int m0 = kmask_s[rr][0], m1 = kmask_s[rr][1];
        float a0, a1;
        if (m0 && m1) { a0=0.f; a1=0.f; if (hd==0) bothm_s[rr]=1; }
        else {
            if (hd==0) bothm_s[rr]=0;
            if (m0)      { a0=0.f; a1=1.f; }
            else if (m1) { a0=1.f; a1=0.f; }
            else {
                float mx = fmaxf(s0,s1);
                float e0 = __expf(s0-mx), e1 = __expf(s1-mx);
                float inv = 1.f/(e0+e1);
                a0 = e0*inv; a1 = e1*inv;
            }
        }
        attn_s[rr][hd][0]=a0; attn_s[rr][hd][1]=a1;
    }
    __syncthreads();

    // ---- ctx (v on the fly) -> Y_bf ----
    {
        const int hd = w>>1;
        const float4 vcj = ((const float4*)(ws+WS_VC))[jj];
        const float vbj = ws[WS_VB+jj];
        #pragma unroll
        for (int reg=0;reg<4;reg++){
            int tok = quad*4 + reg;
            float4 m0v = *(const float4*)&obs_m[tok][0];
            float4 m1v = *(const float4*)&obs_m[tok][4];
            float v0 = dot4(vcj,m0v)+vbj, v1 = dot4(vcj,m1v)+vbj;
            float cx = attn_s[tok][hd][0]*v0 + attn_s[tok][hd][1]*v1;
            Y_bf[tok*136 + jj] = f2bf(cx);
        }
    }
    __syncthreads();

    // ---- attn_out matvec (matrix 1) + nan guard + residual -> Z_bf ----
    {
        f32x4 acc = {0.f,0.f,0.f,0.f};
        #pragma unroll
        for (int p=0;p<4;p++){
            bf16x8 a = *(const bf16x8*)&Y_bf[col*136 + p*32 + quad*8];
            bf16x8 b = *(const bf16x8*)&pbu[((1*32 + w*4 + p)*64 + l)*8];
            acc = __builtin_amdgcn_mfma_f32_16x16x32_bf16(a, b, acc, 0, 0, 0);
        }
        const float boj = bo[jj];
        #pragma unroll
        for (int reg=0;reg<4;reg++){
            int tok = quad*4 + reg;
            float xv = bf2f(X_bf[tok*136 + jj]);
            float ao = bothm_s[tok] ? 0.f : (acc[reg] + boj);
            Z_bf[tok*136 + jj] = f2bf(xv + ao);
        }
    }
    __syncthreads();

    // ---- mlp0 (matrix 2) + leaky -> Y_bf ----
    {
        f32x4 acc = {0.f,0.f,0.f,0.f};
        #pragma unroll
        for (int p=0;p<4;p++){
            bf16x8 a = *(const bf16x8*)&Z_bf[col*136 + p*32 + quad*8];
            bf16x8 b = *(const bf16x8*)&pbu[((2*32 + w*4 + p)*64 + l)*8];
            acc = __builtin_amdgcn_mfma_f32_16x16x32_bf16(a, b, acc, 0, 0, 0);
        }
        const float b0j = b0[jj];
        #pragma unroll
        for (int reg=0;reg<4;reg++){
            int tok = quad*4 + reg;
            float v = acc[reg] + b0j;
            v = (v > 0.f) ? v : 0.01f*v;
            Y_bf[tok*136 + jj] = f2bf(v);
        }
    }
    __syncthreads();

    // ---- mlp1 (matrix 3) + leaky + fco partial ----
    {
        f32x4 acc = {0.f,0.f,0.f,0.f};
        #pragma unroll
        for (int p=0;p<4;p++){
            bf16x8 a = *(const bf16x8*)&Y_bf[col*136 + p*32 + quad*8];
            bf16x8 b = *(const bf16x8*)&pbu[((3*32 + w*4 + p)*64 + l)*8];
            acc = __builtin_amdgcn_mfma_f32_16x16x32_bf16(a, b, acc, 0, 0, 0);
        }
        const float b1j = b1[jj], fcj = fcw[jj];
        float pv[4];
        #pragma unroll
        for (int reg=0;reg<4;reg++){
            float v = acc[reg] + b1j;
            v = (v > 0.f) ? v : 0.01f*v;
            pv[reg] = v * fcj;
        }
        #pragma unroll
        for (int m=1;m<16;m<<=1){
            #pragma unroll
            for (int reg=0;reg<4;reg++) pv[reg] += __shfl_xor(pv[reg], m);
        }
        if (col==0){
            #pragma unroll
            for (int reg=0;reg<4;reg++) part[quad*4+reg][0][w] = pv[reg];
        }
    }
    __syncthreads();
    if (t<16){
        float a = 0.f;
        #pragma unroll
        for (int k=0;k<8;k++) a += part[t][0][k];
        out[n0 + t] = a + fcb[0];
    }
}

extern "C" void kernel_launch(void* const* d_in, const int* in_sizes, int n_in,
                              void* d_out, int out_size, void* d_ws, size_t ws_size,
                              hipStream_t stream) {
    const float* obs       = (const float*)d_in[0];
    const float* h0        = (const float*)d_in[1];
    const float* enc_air_w = (const float*)d_in[2];
    const float* enc_air_b = (const float*)d_in[3];
    const float* enc_m_w   = (const float*)d_in[4];
    const float* enc_m_b   = (const float*)d_in[5];
    const float* gru_wih   = (const float*)d_in[6];
    const float* gru_whh   = (const float*)d_in[7];
    const float* gru_bih   = (const float*)d_in[8];
    const float* gru_bhh   = (const float*)d_in[9];
    const float* qln_w     = (const float*)d_in[10];
    const float* qln_b     = (const float*)d_in[11];
    const float* kln_w     = (const float*)d_in[12];
    const float* kln_b     = (const float*)d_in[13];
    const float* attn_in_w = (const float*)d_in[14];
    const float* attn_in_b = (const float*)d_in[15];
    const float* attn_out_w= (const float*)d_in[16];
    const float* attn_out_b= (const float*)d_in[17];
    const float* mlp0_w    = (const float*)d_in[18];
    const float* mlp0_b    = (const float*)d_in[19];
    const float* mlp1_w    = (const float*)d_in[20];
    const float* mlp1_b    = (const float*)d_in[21];
    const float* fco_w     = (const float*)d_in[22];
    const float* fco_b     = (const float*)d_in[23];
    float* out = (float*)d_out;
    float* ws  = (float*)d_ws;
    float* air = ws + WS_AIR;

    precompute_kernel<<<dim3(384), dim3(256), 0, stream>>>(
        enc_air_w, enc_air_b, enc_m_w, enc_m_b, gru_wih, gru_bih,
        qln_w, qln_b, kln_w, kln_b, attn_in_w, attn_in_b,
        attn_out_w, mlp0_w, mlp1_w, ws);

    gru_kernel<<<dim3(256), dim3(512), 0, stream>>>(
        obs, h0, gru_whh, gru_bhh, enc_air_b, ws, air, out);

    attnmlp_kernel<<<dim3(N_/16), dim3(512), 0, stream>>>(
        obs, attn_out_b, ws,
        mlp0_b, mlp1_b, fco_w, fco_b,
        air, out);
}

// Round 11
// 363.541 us; speedup vs baseline: 19.2482x; 2.3173x over previous
//
#include <hip/hip_runtime.h>
#include <math.h>

#define B_   4096
#define S_   64
#define H_   128
#define N_   (B_*S_)

// ---- workspace float offsets ----
#define WS_WC    0        // [384][16]  combined obs->gi weights (padded f=16)
#define WS_BC    6144     // [384]      combined gi bias
#define WS_WAP   6528     // [128][16]  padded enc_air_w
#define WS_WQP   8576     // [128][128] wq * qln_w (fp32 copy)
#define WS_SQ    24960    // [128] row sums of wqp
#define WS_EQ    25088    // [128] wq@qln_b + bq
#define WS_KC    25216    // [128][4]  (wk*klnw)@enc_m_w
#define WS_EK1   25728    // [128] (wk*klnw)@enc_m_b
#define WS_SK    25856    // [128] rowsum(wk*klnw)
#define WS_EK2   25984    // [128] wk@kln_b + bk
#define WS_VC    26112    // [128][4]  wv@enc_m_w
#define WS_VB    26624    // [128] wv@enc_m_b + bv
#define WS_MV    26752    // [4] mean weights for keys_raw mean
#define WS_QQ    26756    // [16] 4x4 quadratic form for E[y^2]
#define WS_QLIN  26772    // [4]
#define WS_MBC   26776
#define WS_C0    26777
#define WS_PB    27392    // attnmlp packed bf16 B-frags: 65536 ushort (32768 floats)
#define WS_GB    60160    // gru packed bf16 B-frags: 65536 ushort (32768 floats)
#define WS_AIR   92928    // [N_][128] air_feat buffer

typedef __attribute__((ext_vector_type(8))) short bf16x8;
typedef __attribute__((ext_vector_type(4))) float f32x4;

__device__ __forceinline__ float dot4(float4 a, float4 b){
    return fmaf(a.x,b.x, fmaf(a.y,b.y, fmaf(a.z,b.z, a.w*b.w)));
}
__device__ __forceinline__ unsigned short f2bf(float f){   // RNE fp32->bf16
    union { float f; unsigned u; } v; v.f = f;
    unsigned r = v.u + 0x7FFF + ((v.u >> 16) & 1);
    return (unsigned short)(r >> 16);
}
__device__ __forceinline__ float bf2f(unsigned short u){
    union { unsigned u; float f; } v; v.u = ((unsigned)u) << 16;
    return v.f;
}

// ---------------- precompute folded weights + attnmlp bf16 B-frags ----------------
__global__ void precompute_kernel(
    const float* __restrict__ enc_air_w, const float* __restrict__ enc_air_b,
    const float* __restrict__ enc_m_w,  const float* __restrict__ enc_m_b,
    const float* __restrict__ gru_wih,  const float* __restrict__ gru_bih,
    const float* __restrict__ qln_w, const float* __restrict__ qln_b,
    const float* __restrict__ kln_w, const float* __restrict__ kln_b,
    const float* __restrict__ attn_in_w, const float* __restrict__ attn_in_b,
    const float* __restrict__ attn_out_w,
    const float* __restrict__ mlp0_w, const float* __restrict__ mlp1_w,
    float* __restrict__ ws)
{
    int i = blockIdx.x*blockDim.x + threadIdx.x;
    if (i < 6144) {                       // Wc[o][f] = sum_k wih[o][k]*Wa[k][f]
        int o = i>>4, f = i&15; float a = 0.f;
        if (f < 15) for (int k=0;k<128;k++) a = fmaf(gru_wih[o*128+k], enc_air_w[k*15+f], a);
        ws[WS_WC+i] = a;
    } else if (i < 6528) {                // bc
        int o = i-6144; float a = gru_bih[o];
        for (int k=0;k<128;k++) a = fmaf(gru_wih[o*128+k], enc_air_b[k], a);
        ws[WS_BC+o] = a;
    } else if (i < 8576) {                // Wap padded
        int idx = i-6528; int j = idx>>4, f = idx&15;
        ws[WS_WAP+idx] = (f<15) ? enc_air_w[j*15+f] : 0.f;
    } else if (i < 24960) {               // wqp (fp32 copy)
        int idx = i-8576; int o = idx>>7, j = idx&127;
        ws[WS_WQP+idx] = attn_in_w[o*128+j]*qln_w[j];
    } else if (i < 25088) {               // sq
        int o = i-24960; float a=0.f;
        for (int j=0;j<128;j++) a = fmaf(attn_in_w[o*128+j], qln_w[j], a);
        ws[WS_SQ+o]=a;
    } else if (i < 25216) {               // eq
        int o = i-25088; float a = attn_in_b[o];
        for (int j=0;j<128;j++) a = fmaf(attn_in_w[o*128+j], qln_b[j], a);
        ws[WS_EQ+o]=a;
    } else if (i < 25728) {               // Kc
        int idx = i-25216; int o = idx>>2, f = idx&3; float a=0.f;
        for (int j=0;j<128;j++) a = fmaf(attn_in_w[(128+o)*128+j]*kln_w[j], enc_m_w[j*4+f], a);
        ws[WS_KC+idx]=a;
    } else if (i < 25856) {               // ek1
        int o = i-25728; float a=0.f;
        for (int j=0;j<128;j++) a = fmaf(attn_in_w[(128+o)*128+j]*kln_w[j], enc_m_b[j], a);
        ws[WS_EK1+o]=a;
    } else if (i < 25984) {               // sk
        int o = i-25856; float a=0.f;
        for (int j=0;j<128;j++) a = fmaf(attn_in_w[(128+o)*128+j], kln_w[j], a);
        ws[WS_SK+o]=a;
    } else if (i < 26112) {               // ek2
        int o = i-25984; float a = attn_in_b[128+o];
        for (int j=0;j<128;j++) a = fmaf(attn_in_w[(128+o)*128+j], kln_b[j], a);
        ws[WS_EK2+o]=a;
    } else if (i < 26624) {               // Vc
        int idx = i-26112; int o = idx>>2, f = idx&3; float a=0.f;
        for (int j=0;j<128;j++) a = fmaf(attn_in_w[(256+o)*128+j], enc_m_w[j*4+f], a);
        ws[WS_VC+idx]=a;
    } else if (i < 26752) {               // vb
        int o = i-26624; float a = attn_in_b[256+o];
        for (int j=0;j<128;j++) a = fmaf(attn_in_w[(256+o)*128+j], enc_m_b[j], a);
        ws[WS_VB+o]=a;
    } else if (i < 26756) {               // Mv
        int f = i-26752; float a=0.f;
        for (int j=0;j<128;j++) a += enc_m_w[j*4+f];
        ws[WS_MV+f]=a*(1.f/128.f);
    } else if (i < 26772) {               // QQ
        int idx = i-26756; int a4 = idx>>2, b4 = idx&3; float a=0.f;
        for (int j=0;j<128;j++) a = fmaf(enc_m_w[j*4+a4], enc_m_w[j*4+b4], a);
        ws[WS_QQ+idx]=a*(1.f/128.f);
    } else if (i < 26776) {               // qlin
        int f = i-26772; float a=0.f;
        for (int j=0;j<128;j++) a = fmaf(enc_m_b[j], enc_m_w[j*4+f], a);
        ws[WS_QLIN+f]=a*(2.f/128.f);
    } else if (i == 26776) {
        float a=0.f; for (int j=0;j<128;j++) a += enc_m_b[j];
        ws[WS_MBC]=a*(1.f/128.f);
    } else if (i == 26777) {
        float a=0.f; for (int j=0;j<128;j++) a = fmaf(enc_m_b[j], enc_m_b[j], a);
        ws[WS_C0]=a*(1.f/128.f);
    } else if (i >= 32768 && i < 98304) {
        // attnmlp packed bf16 B-fragments (R10 verified)
        int idx = i - 32768;              // 0..65535
        int i8 = idx & 7, l = (idx>>3)&63, p = (idx>>9)&3, wv = (idx>>11)&7, mm = idx>>14;
        int n = 16*wv + (l&15);
        int k = 32*p + ((l>>4)<<3) + i8;
        float v;
        if      (mm==0) v = attn_in_w[n*128+k]*qln_w[k];   // wqp (folded q-LN)
        else if (mm==1) v = attn_out_w[n*128+k];
        else if (mm==2) v = mlp0_w[n*128+k];
        else            v = mlp1_w[n*128+k];
        ((unsigned short*)(ws+WS_PB))[idx] = f2bf(v);
    }
}

// ---------------- pack GRU bf16 B-frags (after precompute: reads WS_WC/WS_WAP) ----
// frag id f: 0..4 = r-gate chunks p=0..4; 5..9 = z-gate; 10..13 = n-gate (h only);
// 14 = gin (Wc_n obs); 15 = ae (Wap obs). n_col = 16w + (l&15).
__global__ void pack_gru_kernel(const float* __restrict__ whh, float* __restrict__ ws)
{
    int idx = blockIdx.x*blockDim.x + threadIdx.x;   // [0, 65536)
    int i8 = idx&7, l=(idx>>3)&63, w=(idx>>9)&7, f=idx>>12;
    int n = 16*w + (l&15);
    int k = ((l>>4)<<3) + i8;       // 0..31 within chunk
    float v = 0.f;
    if (f < 5) {
        int kk = f*32 + k;
        if (kk < 128) v = whh[n*128 + kk];
        else { int kl = kk-128; if (kl<16) v = ws[WS_WC + n*16 + kl]; }
    } else if (f < 10) {
        int kk = (f-5)*32 + k;
        if (kk < 128) v = whh[(128+n)*128 + kk];
        else { int kl = kk-128; if (kl<16) v = ws[WS_WC + (128+n)*16 + kl]; }
    } else if (f < 14) {
        int kk = (f-10)*32 + k;
        v = whh[(256+n)*128 + kk];
    } else if (f == 14) {
        if (k < 16) v = ws[WS_WC + (256+n)*16 + k];
    } else {
        if (k < 16) v = ws[WS_WAP + n*16 + k];
    }
    ((unsigned short*)(ws+WS_GB))[idx] = f2bf(v);
}

// ---------------- Kernel A: GRU via bf16 MFMA ----------------
// 256 blocks x 16 tokens x 512 thr (8 waves). Wave w owns j in [16w,16w+16).
// A = [h(128) | obs(16) | 0(16)] bf16 in LDS (per-step restaged); h fp32 dbuf
// for the recurrence 'hold'. 16 MFMA/wave/step; finalize is per-lane (no shfl).
__global__ __launch_bounds__(512) __attribute__((amdgpu_waves_per_eu(2, 2)))
void gru_kernel(
    const float* __restrict__ obs, const float* __restrict__ h0,
    const float* __restrict__ bhh, const float* __restrict__ ba,
    const float* __restrict__ ws,
    float* __restrict__ air, float* __restrict__ out)
{
    __shared__ __align__(16) unsigned short Abf[2][16*168];  // [token][k], pitch 168 shorts
    __shared__ float h32[2][16*132];
    __shared__ float air_s[16*132];

    const int t = threadIdx.x;
    const int w = t>>6;          // wave 0..7
    const int l = t&63;
    const int quad = l>>4;
    const int col  = l&15;
    const int jj   = 16*w + col; // output column j
    const int row0 = blockIdx.x*16;

    // --- B-frags (loop-invariant; 16 x bf16x8 = 64 regs, AGPR-friendly) ---
    const unsigned short* gb = (const unsigned short*)(ws + WS_GB);
    bf16x8 bf[16];
    #pragma unroll
    for (int f=0; f<16; f++) bf[f] = *(const bf16x8*)&gb[(f*8 + w)*512 + l*8];

    // --- per-lane biases (j fixed) ---
    const float bcrt = ws[WS_BC+jj]     + bhh[jj];
    const float bczt = ws[WS_BC+128+jj] + bhh[128+jj];
    const float bcn  = ws[WS_BC+256+jj];
    const float bhn  = bhh[256+jj];
    const float baj  = ba[jj];

    // --- init: h0 (fp32 + bf16), obs(0), zero pad k in [144,160) both buffers ---
    {
        int rr = t>>5, c0 = (t&31)*4;
        float4 hv = *(const float4*)&h0[(size_t)(row0+rr)*128 + c0];
        *(float4*)&h32[0][rr*132 + c0] = hv;
        unsigned long long pk = (unsigned long long)f2bf(hv.x)
              | ((unsigned long long)f2bf(hv.y)<<16)
              | ((unsigned long long)f2bf(hv.z)<<32)
              | ((unsigned long long)f2bf(hv.w)<<48);
        *(unsigned long long*)&Abf[0][rr*168 + c0] = pk;
    }
    if (t < 256){
        int tok = t>>4, c = t&15;
        float o = (c<15) ? obs[((size_t)(row0+tok)*64 + 0)*15 + c] : 0.f;
        Abf[0][tok*168 + 128 + c] = f2bf(o);
    } else {
        int idx = t-256; int tok = idx>>4, kk = 144 + (idx&15);
        Abf[0][tok*168 + kk] = 0;
        Abf[1][tok*168 + kk] = 0;
    }
    __syncthreads();

    for (int s=0; s<64; s++){
        const unsigned short* Ac = Abf[s&1];
        unsigned short*       An = Abf[(s+1)&1];
        const float* hc = h32[s&1];
        float*       hx = h32[(s+1)&1];

        // prefetch obs(s+1)
        float obs_pf = 0.f;
        if (t < 256){
            int tok = t>>4, c = t&15;
            int sn = (s<63) ? s+1 : s;
            obs_pf = (c<15) ? obs[((size_t)(row0+tok)*64 + sn)*15 + c] : 0.f;
        }

        // A-frags: token = col (m dim), k = 32p + quad*8 + i
        bf16x8 a0 = *(const bf16x8*)&Ac[col*168 +   0 + quad*8];
        bf16x8 a1 = *(const bf16x8*)&Ac[col*168 +  32 + quad*8];
        bf16x8 a2 = *(const bf16x8*)&Ac[col*168 +  64 + quad*8];
        bf16x8 a3 = *(const bf16x8*)&Ac[col*168 +  96 + quad*8];
        bf16x8 a4 = *(const bf16x8*)&Ac[col*168 + 128 + quad*8];

        f32x4 aR = {0.f,0.f,0.f,0.f};
        f32x4 aZ = {0.f,0.f,0.f,0.f};
        f32x4 aN = {0.f,0.f,0.f,0.f};
        f32x4 aG = {0.f,0.f,0.f,0.f};
        f32x4 aE = {0.f,0.f,0.f,0.f};
        aR = __builtin_amdgcn_mfma_f32_16x16x32_bf16(a0, bf[0],  aR, 0,0,0);
        aR = __builtin_amdgcn_mfma_f32_16x16x32_bf16(a1, bf[1],  aR, 0,0,0);
        aR = __builtin_amdgcn_mfma_f32_16x16x32_bf16(a2, bf[2],  aR, 0,0,0);
        aR = __builtin_amdgcn_mfma_f32_16x16x32_bf16(a3, bf[3],  aR, 0,0,0);
        aR = __builtin_amdgcn_mfma_f32_16x16x32_bf16(a4, bf[4],  aR, 0,0,0);
        aZ = __builtin_amdgcn_mfma_f32_16x16x32_bf16(a0, bf[5],  aZ, 0,0,0);
        aZ = __builtin_amdgcn_mfma_f32_16x16x32_bf16(a1, bf[6],  aZ, 0,0,0);
        aZ = __builtin_amdgcn_mfma_f32_16x16x32_bf16(a2, bf[7],  aZ, 0,0,0);
        aZ = __builtin_amdgcn_mfma_f32_16x16x32_bf16(a3, bf[8],  aZ, 0,0,0);
        aZ = __builtin_amdgcn_mfma_f32_16x16x32_bf16(a4, bf[9],  aZ, 0,0,0);
        aN = __builtin_amdgcn_mfma_f32_16x16x32_bf16(a0, bf[10], aN, 0,0,0);
        aN = __builtin_amdgcn_mfma_f32_16x16x32_bf16(a1, bf[11], aN, 0,0,0);
        aN = __builtin_amdgcn_mfma_f32_16x16x32_bf16(a2, bf[12], aN, 0,0,0);
        aN = __builtin_amdgcn_mfma_f32_16x16x32_bf16(a3, bf[13], aN, 0,0,0);
        aG = __builtin_amdgcn_mfma_f32_16x16x32_bf16(a4, bf[14], aG, 0,0,0);
        aE = __builtin_amdgcn_mfma_f32_16x16x32_bf16(a4, bf[15], aE, 0,0,0);

        // finalize: D row = token = quad*4+reg, col = jj (per-lane, no shuffles)
        #pragma unroll
        for (int reg=0; reg<4; reg++){
            int tok = quad*4 + reg;
            float rg = 1.f/(1.f+__expf(-(aR[reg] + bcrt)));
            float zg = 1.f/(1.f+__expf(-(aZ[reg] + bczt)));
            float nx = fmaf(rg, aN[reg] + bhn, aG[reg] + bcn);
            float e2 = __expf(2.f*nx);
            float ng = 1.f - 2.f/(e2+1.f);            // tanh(nx)
            float hold = hc[tok*132 + jj];
            float hn = fmaf(zg, hold-ng, ng);         // (1-z)n + z*h
            hx[tok*132 + jj] = hn;
            An[tok*168 + jj] = f2bf(hn);
            air_s[tok*132 + jj] = hn + (aE[reg] + baj);
            if (s==63) out[(size_t)N_ + (size_t)(row0+tok)*128 + jj] = hn;
        }
        __syncthreads();   // bar_1: Ac/hc reads done; An(h)/hx/air_s written

        // coalesced air write + commit obs(s+1) into An chunk 4
        {
            int rr = t>>5, c0 = (t&31)*4;
            float4 av = *(const float4*)&air_s[rr*132 + c0];
            *(float4*)&air[((size_t)(row0+rr)*64 + s)*128 + c0] = av;
        }
        if (t < 256){
            int tok = t>>4, c = t&15;
            An[tok*168 + 128 + c] = f2bf(obs_pf);
        }
        __syncthreads();   // bar_2: An complete
    }
}

// ---------------- Kernel B: attention + MLP via bf16 MFMA (R10 verified) ----------------
__global__ __launch_bounds__(512) void attnmlp_kernel(
    const float* __restrict__ obs, const float* __restrict__ bo,
    const float* __restrict__ ws,
    const float* __restrict__ b0, const float* __restrict__ b1,
    const float* __restrict__ fcw, const float* __restrict__ fcb,
    const float* __restrict__ air, float* __restrict__ out)
{
    __shared__ __align__(16) unsigned short X_bf[16*136];
    __shared__ __align__(16) unsigned short Y_bf[16*136];
    __shared__ __align__(16) unsigned short Z_bf[16*136];
    __shared__ float obs_m[16][12];
    __shared__ float part[16][2][8];
    __shared__ float attn_s[16][4][2];
    __shared__ float mu_s[16], rs_s[16];
    __shared__ float kmu_s[16][2], krs_s[16][2];
    __shared__ int   kmask_s[16][2];
    __shared__ int   bothm_s[16];

    const int t = threadIdx.x;
    const int w = t>>6;
    const int l = t&63;
    const int quad = l>>4;
    const int col  = l&15;
    const int jj   = 16*w + col;
    const int n0 = blockIdx.x*16;

    const unsigned short* pbu = (const unsigned short*)(ws + WS_PB);

    {
        int rr = t>>5, c0 = (t&31)*4;
        float4 xv = *(const float4*)&air[(size_t)(n0+rr)*128 + c0];
        unsigned long long pk = (unsigned long long)f2bf(xv.x)
              | ((unsigned long long)f2bf(xv.y)<<16)
              | ((unsigned long long)f2bf(xv.z)<<32)
              | ((unsigned long long)f2bf(xv.w)<<48);
        *(unsigned long long*)&X_bf[rr*136 + c0] = pk;
        float sm = xv.x+xv.y+xv.z+xv.w;
        float s2 = fmaf(xv.x,xv.x, fmaf(xv.y,xv.y, fmaf(xv.z,xv.z, xv.w*xv.w)));
        #pragma unroll
        for (int m=1;m<32;m<<=1){ sm += __shfl_xor(sm,m); s2 += __shfl_xor(s2,m); }
        if ((t&31)==0){
            float mu = sm*(1.f/128.f);
            float var = s2*(1.f/128.f) - mu*mu;
            mu_s[rr]=mu; rs_s[rr]=rsqrtf(var+1e-5f);
        }
    }
    if (t>=128 && t<256){
        int idx = t-128; int rr = idx>>3, f = idx&7;
        obs_m[rr][f] = obs[(size_t)(n0+rr)*15 + f];
    }
    if (t<32){
        int rr = t&15, mi = t>>4;
        const float* mp = &obs[(size_t)(n0+rr)*15 + mi*4];
        float m0=mp[0], m1=mp[1], m2=mp[2], m3=mp[3];
        const float tol1 = 1e-8f + 1e-5f, tol0 = 1e-8f;
        kmask_s[rr][mi] = (fabsf(m0-1.f)<=tol1)&&(fabsf(m1)<=tol0)&&
                          (fabsf(m2-1.f)<=tol1)&&(fabsf(m3)<=tol0);
        float mv[4]={m0,m1,m2,m3};
        float mu = ws[WS_MBC];
        #pragma unroll
        for (int f=0;f<4;f++) mu = fmaf(ws[WS_MV+f], mv[f], mu);
        float e2 = ws[WS_C0];
        #pragma unroll
        for (int a4=0;a4<4;a4++){
            e2 = fmaf(ws[WS_QLIN+a4], mv[a4], e2);
            #pragma unroll
            for (int b4=0;b4<4;b4++) e2 = fmaf(ws[WS_QQ+a4*4+b4]*mv[a4], mv[b4], e2);
        }
        float var = e2 - mu*mu;
        kmu_s[rr][mi]=mu; krs_s[rr][mi]=rsqrtf(var+1e-5f);
    }
    __syncthreads();

    {
        f32x4 acc = {0.f,0.f,0.f,0.f};
        #pragma unroll
        for (int p=0;p<4;p++){
            bf16x8 a = *(const bf16x8*)&X_bf[col*136 + p*32 + quad*8];
            bf16x8 b = *(const bf16x8*)&pbu[((0*32 + w*4 + p)*64 + l)*8];
            acc = __builtin_amdgcn_mfma_f32_16x16x32_bf16(a, b, acc, 0, 0, 0);
        }
        const float sqj = ws[WS_SQ+jj], eqj = ws[WS_EQ+jj];
        const float4 kcj = ((const float4*)(ws+WS_KC))[jj];
        const float ek1j = ws[WS_EK1+jj], skj = ws[WS_SK+jj], ek2j = ws[WS_EK2+jj];
        float p0v[4], p1v[4];
        #pragma unroll
        for (int reg=0;reg<4;reg++){
            int tok = quad*4 + reg;
            float qv = fmaf(rs_s[tok], acc[reg] - mu_s[tok]*sqj, eqj);
            float4 m0v = *(const float4*)&obs_m[tok][0];
            float4 m1v = *(const float4*)&obs_m[tok][4];
            float k0 = fmaf(krs_s[tok][0], dot4(kcj,m0v)+ek1j - kmu_s[tok][0]*skj, ek2j);
            float k1 = fmaf(krs_s[tok][1], dot4(kcj,m1v)+ek1j - kmu_s[tok][1]*skj, ek2j);
            p0v[reg] = qv*k0; p1v[reg] = qv*k1;
        }
        #pragma unroll
        for (int m=1;m<16;m<<=1){
            #pragma unroll
            for (int reg=0;reg<4;reg++){
                p0v[reg] += __shfl_xor(p0v[reg], m);
                p1v[reg] += __shfl_xor(p1v[reg], m);
            }
        }
        if (col==0){
            #pragma unroll
            for (int reg=0;reg<4;reg++){
                part[quad*4+reg][0][w] = p0v[reg];
                part[quad*4+reg][1][w] = p1v[reg];
            }
        }
    }
    __syncthreads();

    if (t<64){
        int rr = t&15, hd = t>>4;
        float s0 = part[rr][0][2*hd] + part[rr][0][2*hd+1];
        float s1 = part[rr][1][2*hd] + part[rr][1][2*hd+1];
        const float scale = 0.17677669529663687f;  // 1/sqrt(32)
        s0 *= scale; s1 *= scale;
        int m0 = kmask_s[rr][0], m1 = kmask_s[rr][1];
        float a0, a1;
        if (m0 && m1) { a0=0.f; a1=0.f; if (hd==0) bothm_s[rr]=1; }
        else {
            if (hd==0) bothm_s[rr]=0;
            if (m0)      { a0=0.f; a1=1.f; }
            else if (m1) { a0=1.f; a1=0.f; }
            else {
                float mx = fmaxf(s0,s1);
                float e0 = __expf(s0-mx), e1 = __expf(s1-mx);
                float inv = 1.f/(e0+e1);
                a0 = e0*inv; a1 = e1*inv;
            }
        }
        attn_s[rr][hd][0]=a0; attn_s[rr][hd][1]=a1;
    }
    __syncthreads();

    {
        const int hd = w>>1;
        const float4 vcj = ((const float4*)(ws+WS_VC))[jj];
        const float vbj = ws[WS_VB+jj];
        #pragma unroll
        for (int reg=0;reg<4;reg++){
            int tok = quad*4 + reg;
            float4 m0v = *(const float4*)&obs_m[tok][0];
            float4 m1v = *(const float4*)&obs_m[tok][4];
            float v0 = dot4(vcj,m0v)+vbj, v1 = dot4(vcj,m1v)+vbj;
            float cx = attn_s[tok][hd][0]*v0 + attn_s[tok][hd][1]*v1;
            Y_bf[tok*136 + jj] = f2bf(cx);
        }
    }
    __syncthreads();

    {
        f32x4 acc = {0.f,0.f,0.f,0.f};
        #pragma unroll
        for (int p=0;p<4;p++){
            bf16x8 a = *(const bf16x8*)&Y_bf[col*136 + p*32 + quad*8];
            bf16x8 b = *(const bf16x8*)&pbu[((1*32 + w*4 + p)*64 + l)*8];
            acc = __builtin_amdgcn_mfma_f32_16x16x32_bf16(a, b, acc, 0, 0, 0);
        }
        const float boj = bo[jj];
        #pragma unroll
        for (int reg=0;reg<4;reg++){
            int tok = quad*4 + reg;
            float xv = bf2f(X_bf[tok*136 + jj]);
            float ao = bothm_s[tok] ? 0.f : (acc[reg] + boj);
            Z_bf[tok*136 + jj] = f2bf(xv + ao);
        }
    }
    __syncthreads();

    {
        f32x4 acc = {0.f,0.f,0.f,0.f};
        #pragma unroll
        for (int p=0;p<4;p++){
            bf16x8 a = *(const bf16x8*)&Z_bf[col*136 + p*32 + quad*8];
            bf16x8 b = *(const bf16x8*)&pbu[((2*32 + w*4 + p)*64 + l)*8];
            acc = __builtin_amdgcn_mfma_f32_16x16x32_bf16(a, b, acc, 0, 0, 0);
        }
        const float b0j = b0[jj];
        #pragma unroll
        for (int reg=0;reg<4;reg++){
            int tok = quad*4 + reg;
            float v = acc[reg] + b0j;
            v = (v > 0.f) ? v : 0.01f*v;
            Y_bf[tok*136 + jj] = f2bf(v);
        }
    }
    __syncthreads();

    {
        f32x4 acc = {0.f,0.f,0.f,0.f};
        #pragma unroll
        for (int p=0;p<4;p++){
            bf16x8 a = *(const bf16x8*)&Y_bf[col*136 + p*32 + quad*8];
            bf16x8 b = *(const bf16x8*)&pbu[((3*32 + w*4 + p)*64 + l)*8];
            acc = __builtin_amdgcn_mfma_f32_16x16x32_bf16(a, b, acc, 0, 0, 0);
        }
        const float b1j = b1[jj], fcj = fcw[jj];
        float pv[4];
        #pragma unroll
        for (int reg=0;reg<4;reg++){
            float v = acc[reg] + b1j;
            v = (v > 0.f) ? v : 0.01f*v;
            pv[reg] = v * fcj;
        }
        #pragma unroll
        for (int m=1;m<16;m<<=1){
            #pragma unroll
            for (int reg=0;reg<4;reg++) pv[reg] += __shfl_xor(pv[reg], m);
        }
        if (col==0){
            #pragma unroll
            for (int reg=0;reg<4;reg++) part[quad*4+reg][0][w] = pv[reg];
        }
    }
    __syncthreads();
    if (t<16){
        float a = 0.f;
        #pragma unroll
        for (int k=0;k<8;k++) a += part[t][0][k];
        out[n0 + t] = a + fcb[0];
    }
}

extern "C" void kernel_launch(void* const* d_in, const int* in_sizes, int n_in,
                              void* d_out, int out_size, void* d_ws, size_t ws_size,
                              hipStream_t stream) {
    const float* obs       = (const float*)d_in[0];
    const float* h0        = (const float*)d_in[1];
    const float* enc_air_w = (const float*)d_in[2];
    const float* enc_air_b = (const float*)d_in[3];
    const float* enc_m_w   = (const float*)d_in[4];
    const float* enc_m_b   = (const float*)d_in[5];
    const float* gru_wih   = (const float*)d_in[6];
    const float* gru_whh   = (const float*)d_in[7];
    const float* gru_bih   = (const float*)d_in[8];
    const float* gru_bhh   = (const float*)d_in[9];
    const float* qln_w     = (const float*)d_in[10];
    const float* qln_b     = (const float*)d_in[11];
    const float* kln_w     = (const float*)d_in[12];
    const float* kln_b     = (const float*)d_in[13];
    const float* attn_in_w = (const float*)d_in[14];
    const float* attn_in_b = (const float*)d_in[15];
    const float* attn_out_w= (const float*)d_in[16];
    const float* attn_out_b= (const float*)d_in[17];
    const float* mlp0_w    = (const float*)d_in[18];
    const float* mlp0_b    = (const float*)d_in[19];
    const float* mlp1_w    = (const float*)d_in[20];
    const float* mlp1_b    = (const float*)d_in[21];
    const float* fco_w     = (const float*)d_in[22];
    const float* fco_b     = (const float*)d_in[23];
    float* out = (float*)d_out;
    float* ws  = (float*)d_ws;
    float* air = ws + WS_AIR;

    precompute_kernel<<<dim3(384), dim3(256), 0, stream>>>(
        enc_air_w, enc_air_b, enc_m_w, enc_m_b, gru_wih, gru_bih,
        qln_w, qln_b, kln_w, kln_b, attn_in_w, attn_in_b,
        attn_out_w, mlp0_w, mlp1_w, ws);

    pack_gru_kernel<<<dim3(256), dim3(256), 0, stream>>>(gru_whh, ws);

    gru_kernel<<<dim3(256), dim3(512), 0, stream>>>(
        obs, h0, gru_bhh, enc_air_b, ws, air, out);

    attnmlp_kernel<<<dim3(N_/16), dim3(512), 0, stream>>>(
        obs, attn_out_b, ws,
        mlp0_b, mlp1_b, fco_w, fco_b,
        air, out);
}